// Round 2
// baseline (845.859 us; speedup 1.0000x reference)
//
#include <hip/hip_runtime.h>
#include <hip/hip_bf16.h>
#include <math.h>

#define N_NODES_C 50000
#define NEG_SLOPE 0.2f
#define EPS_ 1e-16f

__device__ __forceinline__ float lrelu(float x){ return x > 0.f ? x : NEG_SLOPE * x; }

// ---------------- CSR build ----------------
__global__ void hist_k(const int* __restrict__ dstv, int* __restrict__ counts, int E){
  int t = blockIdx.x * blockDim.x + threadIdx.x;
  if (t < E) atomicAdd(&counts[dstv[t]], 1);
}

__global__ void chunksum_k(const int* __restrict__ counts, int* __restrict__ sums, int n){
  __shared__ int lds[4];
  int base = blockIdx.x * 1024;
  int t = threadIdx.x; // 256
  int s = 0;
  for (int i = t; i < 1024; i += 256){ int idx = base + i; s += (idx < n) ? counts[idx] : 0; }
  for (int d = 32; d >= 1; d >>= 1) s += __shfl_xor(s, d);
  if ((t & 63) == 0) lds[t >> 6] = s;
  __syncthreads();
  if (t == 0) sums[blockIdx.x] = lds[0] + lds[1] + lds[2] + lds[3];
}

__global__ void chunkscan_k(const int* __restrict__ sums, int* __restrict__ offs,
                            int* __restrict__ row_ptr, int nblocks, int n){
  int l = threadIdx.x; // 64
  int v = (l < nblocks) ? sums[l] : 0;
  int x = v;
  for (int d = 1; d < 64; d <<= 1){ int y = __shfl_up(x, d); if (l >= d) x += y; }
  if (l < nblocks) offs[l] = x - v;
  if (l == nblocks - 1) row_ptr[n] = x;
}

__global__ void scan_k(const int* __restrict__ counts, const int* __restrict__ offs,
                       int* __restrict__ row_ptr, int* __restrict__ fill, int n){
  __shared__ int ws[16];
  int base = blockIdx.x * 1024; int t = threadIdx.x; int idx = base + t;
  int v = (idx < n) ? counts[idx] : 0;
  int lane = t & 63, wid = t >> 6;
  int x = v;
  for (int d = 1; d < 64; d <<= 1){ int y = __shfl_up(x, d); if (lane >= d) x += y; }
  if (lane == 63) ws[wid] = x;
  __syncthreads();
  if (t < 16){ int y = ws[t]; for (int d = 1; d < 16; d <<= 1){ int z = __shfl_up(y, d); if (t >= d) y += z; } ws[t] = y; }
  __syncthreads();
  int excl = x - v + (wid ? ws[wid - 1] : 0) + offs[blockIdx.x];
  if (idx < n){ row_ptr[idx] = excl; fill[idx] = excl; }
}

__global__ void scatter_k(const int* __restrict__ srcv, const int* __restrict__ dstv,
                          int* __restrict__ fill, int* __restrict__ esrc, int E){
  int t = blockIdx.x * blockDim.x + threadIdx.x;
  if (t < E){ int p = atomicAdd(&fill[dstv[t]], 1); esrc[p] = srcv[t]; }
}

// ---------------- GEMM: C[n][J] = A[n][K] @ W[K][J] ----------------
template<int K, int J>
__global__ __launch_bounds__((J/4)*8) void gemm_k(const float* __restrict__ A, const float* __restrict__ W,
                                                  float* __restrict__ Cout, int n){
  constexpr int NQ = J / 4;       // col quads
  constexpr int NT = NQ * 8;      // threads
  constexpr int ROWS = 32;
  constexpr int KP = K + 4;       // padded LDS row stride (words), keeps 16B align, breaks bank aliasing
  __shared__ float Wl[K * J];
  __shared__ float Al[ROWS * KP];
  int t = threadIdx.x;
  for (int i = t; i < K * J / 4; i += NT) ((float4*)Wl)[i] = ((const float4*)W)[i];
  int rbase = blockIdx.x * ROWS;
  for (int i = t; i < ROWS * (K / 4); i += NT){
    int r = i / (K / 4), kq = i % (K / 4);
    float4 v = make_float4(0.f, 0.f, 0.f, 0.f);
    if (rbase + r < n) v = ((const float4*)(A + (size_t)(rbase + r) * K))[kq];
    *((float4*)(Al + r * KP + kq * 4)) = v;
  }
  __syncthreads();
  int jq = t % NQ; int rb = t / NQ; // rb in 0..7
  float4 acc[4];
  #pragma unroll
  for (int i = 0; i < 4; i++) acc[i] = make_float4(0.f, 0.f, 0.f, 0.f);
  for (int k = 0; k < K; k++){
    float4 w = *((const float4*)(Wl + k * J + jq * 4));
    #pragma unroll
    for (int i = 0; i < 4; i++){
      float a = Al[(rb + i * 8) * KP + k];
      acc[i].x += a * w.x; acc[i].y += a * w.y; acc[i].z += a * w.z; acc[i].w += a * w.w;
    }
  }
  #pragma unroll
  for (int i = 0; i < 4; i++){
    int r = rbase + rb + i * 8;
    if (r < n) *((float4*)(Cout + (size_t)r * J + jq * 4)) = acc[i];
  }
}

// ---------------- alpha_src / alpha_dst: wave per node ----------------
template<int HEADS, int C>
__global__ void alpha_k(const float* __restrict__ H, const float* __restrict__ a_s, const float* __restrict__ a_d,
                        float* __restrict__ asrc, float* __restrict__ adst, int n){
  constexpr int J = HEADS * C;
  int node = blockIdx.x * (blockDim.x >> 6) + (threadIdx.x >> 6);
  if (node >= n) return;
  int lane = threadIdx.x & 63;
  const float* hr = H + (size_t)node * J;
  float h0 = hr[lane];
  float s0 = h0 * a_s[lane], d0 = h0 * a_d[lane];
  float s1 = 0.f, d1 = 0.f;
  if (J > 64){
    if (lane < J - 64){
      float h1 = hr[lane + 64];
      s1 = h1 * a_s[lane + 64]; d1 = h1 * a_d[lane + 64];
    }
  }
  if (HEADS == 1){
    float s = s0 + s1, dd = d0 + d1;
    for (int d = 32; d >= 1; d >>= 1){ s += __shfl_xor(s, d); dd += __shfl_xor(dd, d); }
    if (lane == 0){ asrc[node] = s; adst[node] = dd; }
  } else { // HEADS=3, C=32, J=96
    for (int d = 16; d >= 1; d >>= 1){
      s0 += __shfl_xor(s0, d); d0 += __shfl_xor(d0, d);
      s1 += __shfl_xor(s1, d); d1 += __shfl_xor(d1, d);
    }
    if (lane == 0){
      asrc[node * 3 + 0] = s0; adst[node * 3 + 0] = d0;
      asrc[node * 3 + 2] = s1; adst[node * 3 + 2] = d1;
    }
    if (lane == 32){ asrc[node * 3 + 1] = s0; adst[node * 3 + 1] = d0; }
  }
}

// ---------------- segment softmax + aggregation: wave per dst node ----------------
template<int HEADS, int C, bool ELU>
__global__ void agg_k(const float* __restrict__ H, const float* __restrict__ asrc, const float* __restrict__ adst,
                      const int* __restrict__ row_ptr, const int* __restrict__ esrc,
                      const float* __restrict__ bias, float* __restrict__ out, int n){
  constexpr int J = HEADS * C;
  int node = blockIdx.x * (blockDim.x >> 6) + (threadIdx.x >> 6);
  if (node >= n) return;
  int lane = threadIdx.x & 63;
  float ad[HEADS], es[HEADS], m[HEADS], denom[HEADS], wh[HEADS];
  #pragma unroll
  for (int h = 0; h < HEADS; h++){
    ad[h] = adst[node * HEADS + h];
    es[h] = lrelu(asrc[node * HEADS + h] + ad[h]); // self-loop logit
    m[h] = es[h];
  }
  int beg = row_ptr[node], end = row_ptr[node + 1];
  // pass 1: segment max (incl. self-loop)
  for (int e = beg; e < end; e++){
    int s = esrc[e];
    #pragma unroll
    for (int h = 0; h < HEADS; h++){ float v = lrelu(asrc[s * HEADS + h] + ad[h]); m[h] = fmaxf(m[h], v); }
  }
  int j0 = lane, j1 = lane + 64;
  const float* hr0 = H + (size_t)node * J;
  float acc0, acc1 = 0.f;
  #pragma unroll
  for (int h = 0; h < HEADS; h++){ wh[h] = __expf(es[h] - m[h]); denom[h] = wh[h]; }
  acc0 = wh[j0 / C] * hr0[j0];
  if (J > 64 && j1 < J) acc1 = wh[j1 / C] * hr0[j1];
  // pass 2: exp-sum + weighted gather
  for (int e = beg; e < end; e++){
    int s = esrc[e];
    #pragma unroll
    for (int h = 0; h < HEADS; h++){
      float v = lrelu(asrc[s * HEADS + h] + ad[h]);
      float w = __expf(v - m[h]);
      wh[h] = w; denom[h] += w;
    }
    const float* hr = H + (size_t)s * J;
    acc0 += wh[j0 / C] * hr[j0];
    if (J > 64 && j1 < J) acc1 += wh[j1 / C] * hr[j1];
  }
  float r0 = acc0 / (denom[j0 / C] + EPS_) + bias[j0];
  if (ELU) r0 = r0 > 0.f ? r0 : __expf(r0) - 1.f;
  out[(size_t)node * J + j0] = r0;
  if (J > 64 && j1 < J){
    float r1 = acc1 / (denom[j1 / C] + EPS_) + bias[j1];
    if (ELU) r1 = r1 > 0.f ? r1 : __expf(r1) - 1.f;
    out[(size_t)node * J + j1] = r1;
  }
}

extern "C" void kernel_launch(void* const* d_in, const int* in_sizes, int n_in,
                              void* d_out, int out_size, void* d_ws, size_t ws_size,
                              hipStream_t stream){
  const float* x   = (const float*)d_in[0];
  const int*   ei  = (const int*)  d_in[1];
  const float* W1  = (const float*)d_in[2];
  const float* as1 = (const float*)d_in[3];
  const float* ad1 = (const float*)d_in[4];
  const float* b1  = (const float*)d_in[5];
  const float* W2  = (const float*)d_in[6];
  const float* as2 = (const float*)d_in[7];
  const float* ad2 = (const float*)d_in[8];
  const float* b2  = (const float*)d_in[9];
  const float* W3  = (const float*)d_in[10];
  const float* as3 = (const float*)d_in[11];
  const float* ad3 = (const float*)d_in[12];
  const float* b3  = (const float*)d_in[13];
  float* out = (float*)d_out;

  const int N = N_NODES_C;
  const int E = in_sizes[1] / 2;
  const int* srcv = ei;
  const int* dstv = ei + E;

  char* ws = (char*)d_ws;
  auto alloc = [&](size_t bytes)->char*{ char* p = ws; ws += (bytes + 255) & ~(size_t)255; return p; };
  int*   counts  = (int*)  alloc((size_t)N * 4);
  int*   row_ptr = (int*)  alloc((size_t)(N + 1) * 4);
  int*   fill    = (int*)  alloc((size_t)N * 4);
  int*   csums   = (int*)  alloc(64 * 4);
  int*   coffs   = (int*)  alloc(64 * 4);
  int*   esrc    = (int*)  alloc((size_t)E * 4);
  float* hbuf    = (float*)alloc((size_t)N * 128 * 4);
  float* feat    = (float*)alloc((size_t)N * 96 * 4);
  float* a_src   = (float*)alloc((size_t)N * 3 * 4);
  float* a_dst   = (float*)alloc((size_t)N * 3 * 4);

  // ---- CSR (by dst), reused by all 3 layers ----
  hipMemsetAsync(counts, 0, (size_t)N * 4, stream);
  hist_k<<<(E + 255) / 256, 256, 0, stream>>>(dstv, counts, E);
  int nch = (N + 1023) / 1024;
  chunksum_k<<<nch, 256, 0, stream>>>(counts, csums, N);
  chunkscan_k<<<1, 64, 0, stream>>>(csums, coffs, row_ptr, nch, N);
  scan_k<<<nch, 1024, 0, stream>>>(counts, coffs, row_ptr, fill, N);
  scatter_k<<<(E + 255) / 256, 256, 0, stream>>>(srcv, dstv, fill, esrc, E);

  int gnode4 = (N + 3) / 4;      // 4 waves (nodes) per 256-thread block
  int grows  = (N + 31) / 32;    // GEMM: 32 rows per block

  // ---- layer 1: 128 -> (3,32), concat, ELU ----
  gemm_k<128, 96><<<grows, 192, 0, stream>>>(x, W1, hbuf, N);
  alpha_k<3, 32><<<gnode4, 256, 0, stream>>>(hbuf, as1, ad1, a_src, a_dst, N);
  agg_k<3, 32, true><<<gnode4, 256, 0, stream>>>(hbuf, a_src, a_dst, row_ptr, esrc, b1, feat, N);

  // ---- layer 2: 96 -> (3,32), concat, ELU ----
  gemm_k<96, 96><<<grows, 192, 0, stream>>>(feat, W2, hbuf, N);
  alpha_k<3, 32><<<gnode4, 256, 0, stream>>>(hbuf, as2, ad2, a_src, a_dst, N);
  agg_k<3, 32, true><<<gnode4, 256, 0, stream>>>(hbuf, a_src, a_dst, row_ptr, esrc, b2, feat, N);

  // ---- layer 3: 96 -> (1,128), mean(=identity for 1 head), no ELU ----
  gemm_k<96, 128><<<grows, 256, 0, stream>>>(feat, W3, hbuf, N);
  alpha_k<1, 128><<<gnode4, 256, 0, stream>>>(hbuf, as3, ad3, a_src, a_dst, N);
  agg_k<1, 128, false><<<gnode4, 256, 0, stream>>>(hbuf, a_src, a_dst, row_ptr, esrc, b3, out, N);
}

// Round 3
// 507.854 us; speedup vs baseline: 1.6656x; 1.6656x over previous
//
#include <hip/hip_runtime.h>
#include <hip/hip_bf16.h>
#include <math.h>

#define N_NODES_C 50000
#define NEG_SLOPE 0.2f
#define EPS_ 1e-16f

__device__ __forceinline__ float lrelu(float x){ return x > 0.f ? x : NEG_SLOPE * x; }

// ---------------- CSR build ----------------
__global__ void hist_k(const int* __restrict__ dstv, int* __restrict__ counts, int E){
  int t = blockIdx.x * blockDim.x + threadIdx.x;
  if (t < E) atomicAdd(&counts[dstv[t]], 1);
}

__global__ void chunksum_k(const int* __restrict__ counts, int* __restrict__ sums, int n){
  __shared__ int lds[4];
  int base = blockIdx.x * 1024;
  int t = threadIdx.x; // 256
  int s = 0;
  for (int i = t; i < 1024; i += 256){ int idx = base + i; s += (idx < n) ? counts[idx] : 0; }
  for (int d = 32; d >= 1; d >>= 1) s += __shfl_xor(s, d);
  if ((t & 63) == 0) lds[t >> 6] = s;
  __syncthreads();
  if (t == 0) sums[blockIdx.x] = lds[0] + lds[1] + lds[2] + lds[3];
}

__global__ void chunkscan_k(const int* __restrict__ sums, int* __restrict__ offs,
                            int* __restrict__ row_ptr, int nblocks, int n){
  int l = threadIdx.x; // 64
  int v = (l < nblocks) ? sums[l] : 0;
  int x = v;
  for (int d = 1; d < 64; d <<= 1){ int y = __shfl_up(x, d); if (l >= d) x += y; }
  if (l < nblocks) offs[l] = x - v;
  if (l == nblocks - 1) row_ptr[n] = x;
}

__global__ void scan_k(const int* __restrict__ counts, const int* __restrict__ offs,
                       int* __restrict__ row_ptr, int* __restrict__ fill, int n){
  __shared__ int ws[16];
  int base = blockIdx.x * 1024; int t = threadIdx.x; int idx = base + t;
  int v = (idx < n) ? counts[idx] : 0;
  int lane = t & 63, wid = t >> 6;
  int x = v;
  for (int d = 1; d < 64; d <<= 1){ int y = __shfl_up(x, d); if (lane >= d) x += y; }
  if (lane == 63) ws[wid] = x;
  __syncthreads();
  if (t < 16){ int y = ws[t]; for (int d = 1; d < 16; d <<= 1){ int z = __shfl_up(y, d); if (t >= d) y += z; } ws[t] = y; }
  __syncthreads();
  int excl = x - v + (wid ? ws[wid - 1] : 0) + offs[blockIdx.x];
  if (idx < n){ row_ptr[idx] = excl; fill[idx] = excl; }
}

__global__ void scatter_k(const int* __restrict__ srcv, const int* __restrict__ dstv,
                          int* __restrict__ fill, int* __restrict__ esrc, int* __restrict__ edst, int E){
  int t = blockIdx.x * blockDim.x + threadIdx.x;
  if (t < E){
    int d = dstv[t];
    int p = atomicAdd(&fill[d], 1);
    esrc[p] = srcv[t];
    edst[p] = d;
  }
}

// ---------------- GEMM: C[n][J] = A[n][K] @ W[K][J] ----------------
template<int K, int J>
__global__ __launch_bounds__((J/4)*8) void gemm_k(const float* __restrict__ A, const float* __restrict__ W,
                                                  float* __restrict__ Cout, int n){
  constexpr int NQ = J / 4;       // col quads
  constexpr int NT = NQ * 8;      // threads
  constexpr int ROWS = 32;
  constexpr int KP = K + 4;
  __shared__ float Wl[K * J];
  __shared__ float Al[ROWS * KP];
  int t = threadIdx.x;
  for (int i = t; i < K * J / 4; i += NT) ((float4*)Wl)[i] = ((const float4*)W)[i];
  int rbase = blockIdx.x * ROWS;
  for (int i = t; i < ROWS * (K / 4); i += NT){
    int r = i / (K / 4), kq = i % (K / 4);
    float4 v = make_float4(0.f, 0.f, 0.f, 0.f);
    if (rbase + r < n) v = ((const float4*)(A + (size_t)(rbase + r) * K))[kq];
    *((float4*)(Al + r * KP + kq * 4)) = v;
  }
  __syncthreads();
  int jq = t % NQ; int rb = t / NQ; // rb in 0..7
  float4 acc[4];
  #pragma unroll
  for (int i = 0; i < 4; i++) acc[i] = make_float4(0.f, 0.f, 0.f, 0.f);
  for (int k = 0; k < K; k++){
    float4 w = *((const float4*)(Wl + k * J + jq * 4));
    #pragma unroll
    for (int i = 0; i < 4; i++){
      float a = Al[(rb + i * 8) * KP + k];
      acc[i].x += a * w.x; acc[i].y += a * w.y; acc[i].z += a * w.z; acc[i].w += a * w.w;
    }
  }
  #pragma unroll
  for (int i = 0; i < 4; i++){
    int r = rbase + rb + i * 8;
    if (r < n) *((float4*)(Cout + (size_t)r * J + jq * 4)) = acc[i];
  }
}

// ---------------- alpha_src / alpha_dst: wave per node ----------------
template<int HEADS, int C>
__global__ void alpha_k(const float* __restrict__ H, const float* __restrict__ a_s, const float* __restrict__ a_d,
                        float* __restrict__ asrc, float* __restrict__ adst, int n){
  constexpr int J = HEADS * C;
  int node = blockIdx.x * (blockDim.x >> 6) + (threadIdx.x >> 6);
  if (node >= n) return;
  int lane = threadIdx.x & 63;
  const float* hr = H + (size_t)node * J;
  float h0 = hr[lane];
  float s0 = h0 * a_s[lane], d0 = h0 * a_d[lane];
  float s1 = 0.f, d1 = 0.f;
  if (J > 64){
    if (lane < J - 64){
      float h1 = hr[lane + 64];
      s1 = h1 * a_s[lane + 64]; d1 = h1 * a_d[lane + 64];
    }
  }
  if (HEADS == 1){
    float s = s0 + s1, dd = d0 + d1;
    for (int d = 32; d >= 1; d >>= 1){ s += __shfl_xor(s, d); dd += __shfl_xor(dd, d); }
    if (lane == 0){ asrc[node] = s; adst[node] = dd; }
  } else { // HEADS=3, C=32, J=96
    for (int d = 16; d >= 1; d >>= 1){
      s0 += __shfl_xor(s0, d); d0 += __shfl_xor(d0, d);
      s1 += __shfl_xor(s1, d); d1 += __shfl_xor(d1, d);
    }
    if (lane == 0){
      asrc[node * 3 + 0] = s0; adst[node * 3 + 0] = d0;
      asrc[node * 3 + 2] = s1; adst[node * 3 + 2] = d1;
    }
    if (lane == 32){ asrc[node * 3 + 1] = s0; adst[node * 3 + 1] = d0; }
  }
}

// ---------------- edge weights (CSR order): w = exp(lrelu(asrc[s]+adst[d])) ----------------
template<int HEADS>
__global__ void ew_k(const float* __restrict__ asrc, const float* __restrict__ adst,
                     const int* __restrict__ esrc, const int* __restrict__ edst,
                     float* __restrict__ ew, int E){
  int t = blockIdx.x * blockDim.x + threadIdx.x;
  if (t >= E) return;
  int s = esrc[t], d = edst[t];
  #pragma unroll
  for (int h = 0; h < HEADS; h++){
    float v = lrelu(asrc[s * HEADS + h] + adst[d * HEADS + h]);
    ew[(size_t)t * HEADS + h] = __expf(v);
  }
}

// ---------------- aggregation: wave per dst node, single pass, precomputed weights ----------------
template<int HEADS, int C, bool ELU>
__global__ void agg_k(const float* __restrict__ H, const float* __restrict__ ew,
                      const float* __restrict__ asrc, const float* __restrict__ adst,
                      const int* __restrict__ row_ptr, const int* __restrict__ esrc,
                      const float* __restrict__ bias, float* __restrict__ out, int n){
  constexpr int J = HEADS * C;
  int node = blockIdx.x * (blockDim.x >> 6) + (threadIdx.x >> 6);
  if (node >= n) return;
  int lane = threadIdx.x & 63;
  int j0 = lane, j1 = lane + 64;
  int h0 = j0 / C;
  int h1 = (J > 64) ? (j1 / C) : 0;
  bool use1 = (J > 64) && (j1 < J);

  // self-loop weight (per-lane for its own head)
  float w0 = __expf(lrelu(asrc[node * HEADS + h0] + adst[node * HEADS + h0]));
  float w1 = use1 ? __expf(lrelu(asrc[node * HEADS + h1] + adst[node * HEADS + h1])) : 0.f;
  const float* hr0 = H + (size_t)node * J;
  float acc0 = w0 * hr0[j0];
  float acc1 = use1 ? w1 * hr0[j1] : 0.f;
  float den0 = w0, den1 = w1;

  int beg = row_ptr[node], end = row_ptr[node + 1];
  int e = beg;
  for (; e + 4 <= end; e += 4){
    int s[4]; float wa[4], wb[4], ha[4], hb[4];
    #pragma unroll
    for (int u = 0; u < 4; u++) s[u] = esrc[e + u];
    #pragma unroll
    for (int u = 0; u < 4; u++){
      wa[u] = ew[(size_t)(e + u) * HEADS + h0];
      wb[u] = use1 ? ew[(size_t)(e + u) * HEADS + h1] : 0.f;
    }
    #pragma unroll
    for (int u = 0; u < 4; u++){
      const float* hr = H + (size_t)s[u] * J;
      ha[u] = hr[j0];
      hb[u] = use1 ? hr[j1] : 0.f;
    }
    #pragma unroll
    for (int u = 0; u < 4; u++){
      acc0 += wa[u] * ha[u]; den0 += wa[u];
      acc1 += wb[u] * hb[u]; den1 += wb[u];
    }
  }
  for (; e < end; e++){
    int s = esrc[e];
    float wa = ew[(size_t)e * HEADS + h0];
    const float* hr = H + (size_t)s * J;
    acc0 += wa * hr[j0]; den0 += wa;
    if (use1){
      float wb = ew[(size_t)e * HEADS + h1];
      acc1 += wb * hr[j1]; den1 += wb;
    }
  }
  float r0 = acc0 / (den0 + EPS_) + bias[j0];
  if (ELU) r0 = r0 > 0.f ? r0 : __expf(r0) - 1.f;
  out[(size_t)node * J + j0] = r0;
  if (use1){
    float r1 = acc1 / (den1 + EPS_) + bias[j1];
    if (ELU) r1 = r1 > 0.f ? r1 : __expf(r1) - 1.f;
    out[(size_t)node * J + j1] = r1;
  }
}

extern "C" void kernel_launch(void* const* d_in, const int* in_sizes, int n_in,
                              void* d_out, int out_size, void* d_ws, size_t ws_size,
                              hipStream_t stream){
  const float* x   = (const float*)d_in[0];
  const int*   ei  = (const int*)  d_in[1];
  const float* W1  = (const float*)d_in[2];
  const float* as1 = (const float*)d_in[3];
  const float* ad1 = (const float*)d_in[4];
  const float* b1  = (const float*)d_in[5];
  const float* W2  = (const float*)d_in[6];
  const float* as2 = (const float*)d_in[7];
  const float* ad2 = (const float*)d_in[8];
  const float* b2  = (const float*)d_in[9];
  const float* W3  = (const float*)d_in[10];
  const float* as3 = (const float*)d_in[11];
  const float* ad3 = (const float*)d_in[12];
  const float* b3  = (const float*)d_in[13];
  float* out = (float*)d_out;

  const int N = N_NODES_C;
  const int E = in_sizes[1] / 2;
  const int* srcv = ei;
  const int* dstv = ei + E;

  char* ws = (char*)d_ws;
  auto alloc = [&](size_t bytes)->char*{ char* p = ws; ws += (bytes + 255) & ~(size_t)255; return p; };
  int*   counts  = (int*)  alloc((size_t)N * 4);
  int*   row_ptr = (int*)  alloc((size_t)(N + 1) * 4);
  int*   fill    = (int*)  alloc((size_t)N * 4);
  int*   csums   = (int*)  alloc(64 * 4);
  int*   coffs   = (int*)  alloc(64 * 4);
  int*   esrc    = (int*)  alloc((size_t)E * 4);
  int*   edst    = (int*)  alloc((size_t)E * 4);
  float* ew      = (float*)alloc((size_t)E * 3 * 4);
  float* hbuf    = (float*)alloc((size_t)N * 128 * 4);
  float* feat    = (float*)alloc((size_t)N * 96 * 4);
  float* a_src   = (float*)alloc((size_t)N * 3 * 4);
  float* a_dst   = (float*)alloc((size_t)N * 3 * 4);

  // ---- CSR (by dst), reused by all 3 layers ----
  hipMemsetAsync(counts, 0, (size_t)N * 4, stream);
  hist_k<<<(E + 255) / 256, 256, 0, stream>>>(dstv, counts, E);
  int nch = (N + 1023) / 1024;
  chunksum_k<<<nch, 256, 0, stream>>>(counts, csums, N);
  chunkscan_k<<<1, 64, 0, stream>>>(csums, coffs, row_ptr, nch, N);
  scan_k<<<nch, 1024, 0, stream>>>(counts, coffs, row_ptr, fill, N);
  scatter_k<<<(E + 255) / 256, 256, 0, stream>>>(srcv, dstv, fill, esrc, edst, E);

  int gnode4 = (N + 3) / 4;      // 4 waves (nodes) per 256-thread block
  int grows  = (N + 31) / 32;    // GEMM: 32 rows per block
  int gedge  = (E + 255) / 256;

  // ---- layer 1: 128 -> (3,32), concat, ELU ----
  gemm_k<128, 96><<<grows, 192, 0, stream>>>(x, W1, hbuf, N);
  alpha_k<3, 32><<<gnode4, 256, 0, stream>>>(hbuf, as1, ad1, a_src, a_dst, N);
  ew_k<3><<<gedge, 256, 0, stream>>>(a_src, a_dst, esrc, edst, ew, E);
  agg_k<3, 32, true><<<gnode4, 256, 0, stream>>>(hbuf, ew, a_src, a_dst, row_ptr, esrc, b1, feat, N);

  // ---- layer 2: 96 -> (3,32), concat, ELU ----
  gemm_k<96, 96><<<grows, 192, 0, stream>>>(feat, W2, hbuf, N);
  alpha_k<3, 32><<<gnode4, 256, 0, stream>>>(hbuf, as2, ad2, a_src, a_dst, N);
  ew_k<3><<<gedge, 256, 0, stream>>>(a_src, a_dst, esrc, edst, ew, E);
  agg_k<3, 32, true><<<gnode4, 256, 0, stream>>>(hbuf, ew, a_src, a_dst, row_ptr, esrc, b2, feat, N);

  // ---- layer 3: 96 -> (1,128), mean(=identity for 1 head), no ELU ----
  gemm_k<96, 128><<<grows, 256, 0, stream>>>(feat, W3, hbuf, N);
  alpha_k<1, 128><<<gnode4, 256, 0, stream>>>(hbuf, as3, ad3, a_src, a_dst, N);
  ew_k<1><<<gedge, 256, 0, stream>>>(a_src, a_dst, esrc, edst, ew, E);
  agg_k<1, 128, false><<<gnode4, 256, 0, stream>>>(hbuf, ew, a_src, a_dst, row_ptr, esrc, b3, out, N);
}

// Round 4
// 457.800 us; speedup vs baseline: 1.8477x; 1.1093x over previous
//
#include <hip/hip_runtime.h>
#include <hip/hip_bf16.h>
#include <hip/hip_fp16.h>
#include <math.h>

#define N_NODES_C 50000
#define NEG_SLOPE 0.2f
#define EPS_ 1e-16f

__device__ __forceinline__ float lrelu(float x){ return x > 0.f ? x : NEG_SLOPE * x; }

// ---------------- CSR build ----------------
__global__ void hist_k(const int* __restrict__ dstv, int* __restrict__ counts, int E){
  int t = blockIdx.x * blockDim.x + threadIdx.x;
  if (t < E) atomicAdd(&counts[dstv[t]], 1);
}

__global__ void chunksum_k(const int* __restrict__ counts, int* __restrict__ sums, int n){
  __shared__ int lds[4];
  int base = blockIdx.x * 1024;
  int t = threadIdx.x; // 256
  int s = 0;
  for (int i = t; i < 1024; i += 256){ int idx = base + i; s += (idx < n) ? counts[idx] : 0; }
  for (int d = 32; d >= 1; d >>= 1) s += __shfl_xor(s, d);
  if ((t & 63) == 0) lds[t >> 6] = s;
  __syncthreads();
  if (t == 0) sums[blockIdx.x] = lds[0] + lds[1] + lds[2] + lds[3];
}

__global__ void chunkscan_k(const int* __restrict__ sums, int* __restrict__ offs,
                            int* __restrict__ row_ptr, int nblocks, int n){
  int l = threadIdx.x; // 64
  int v = (l < nblocks) ? sums[l] : 0;
  int x = v;
  for (int d = 1; d < 64; d <<= 1){ int y = __shfl_up(x, d); if (l >= d) x += y; }
  if (l < nblocks) offs[l] = x - v;
  if (l == nblocks - 1) row_ptr[n] = x;
}

__global__ void scan_k(const int* __restrict__ counts, const int* __restrict__ offs,
                       int* __restrict__ row_ptr, int* __restrict__ fill, int n){
  __shared__ int ws[16];
  int base = blockIdx.x * 1024; int t = threadIdx.x; int idx = base + t;
  int v = (idx < n) ? counts[idx] : 0;
  int lane = t & 63, wid = t >> 6;
  int x = v;
  for (int d = 1; d < 64; d <<= 1){ int y = __shfl_up(x, d); if (lane >= d) x += y; }
  if (lane == 63) ws[wid] = x;
  __syncthreads();
  if (t < 16){ int y = ws[t]; for (int d = 1; d < 16; d <<= 1){ int z = __shfl_up(y, d); if (t >= d) y += z; } ws[t] = y; }
  __syncthreads();
  int excl = x - v + (wid ? ws[wid - 1] : 0) + offs[blockIdx.x];
  if (idx < n){ row_ptr[idx] = excl; fill[idx] = excl; }
}

__global__ void scatter_k(const int* __restrict__ srcv, const int* __restrict__ dstv,
                          int* __restrict__ fill, int* __restrict__ esrc, int E){
  int t = blockIdx.x * blockDim.x + threadIdx.x;
  if (t < E){ int p = atomicAdd(&fill[dstv[t]], 1); esrc[p] = srcv[t]; }
}

// ---------------- fused GEMM + alpha: H(fp16)[n][J] = A[n][K] @ W[K][J]; alpha = H·a ----------------
template<int K, int J, int HEADS>
__global__ __launch_bounds__((J/4)*8) void gemm_alpha_k(
    const float* __restrict__ A, const float* __restrict__ W,
    const float* __restrict__ a_s, const float* __restrict__ a_d,
    __half* __restrict__ Hh, float* __restrict__ asrc, float* __restrict__ adst, int n){
  constexpr int NQ = J / 4;       // col quads
  constexpr int NT = NQ * 8;      // threads
  constexpr int ROWS = 32;
  constexpr int KQ = K / 4;
  constexpr int KQP = KQ + 1;     // padded (in float4 units)
  __shared__ float  Wl[K * J];
  __shared__ float4 Al[ROWS * KQP];
  __shared__ float  als[ROWS * HEADS];
  __shared__ float  ald[ROWS * HEADS];
  int t = threadIdx.x;
  for (int i = t; i < K * J / 4; i += NT) ((float4*)Wl)[i] = ((const float4*)W)[i];
  int rbase = blockIdx.x * ROWS;
  for (int i = t; i < ROWS * KQ; i += NT){
    int r = i / KQ, kq = i % KQ;
    float4 v = make_float4(0.f, 0.f, 0.f, 0.f);
    if (rbase + r < n) v = ((const float4*)(A + (size_t)(rbase + r) * K))[kq];
    Al[r * KQP + kq] = v;
  }
  if (t < ROWS * HEADS){ als[t] = 0.f; ald[t] = 0.f; }
  __syncthreads();
  int jq = t % NQ; int rb = t / NQ; // rb in 0..7
  float4 acc[4];
  #pragma unroll
  for (int i = 0; i < 4; i++) acc[i] = make_float4(0.f, 0.f, 0.f, 0.f);
  for (int kb = 0; kb < KQ; kb++){
    const float* wb = Wl + kb * 4 * J + jq * 4;
    float4 w0 = *(const float4*)(wb);
    float4 w1 = *(const float4*)(wb + J);
    float4 w2 = *(const float4*)(wb + 2 * J);
    float4 w3 = *(const float4*)(wb + 3 * J);
    #pragma unroll
    for (int i = 0; i < 4; i++){
      float4 a = Al[(rb + 8 * i) * KQP + kb];
      acc[i].x += a.x * w0.x + a.y * w1.x + a.z * w2.x + a.w * w3.x;
      acc[i].y += a.x * w0.y + a.y * w1.y + a.z * w2.y + a.w * w3.y;
      acc[i].z += a.x * w0.z + a.y * w1.z + a.z * w2.z + a.w * w3.z;
      acc[i].w += a.x * w0.w + a.y * w1.w + a.z * w2.w + a.w * w3.w;
    }
  }
  // epilogue: fp16 store + per-head alpha partial reduction
  int hh = (jq * 4) / (J / HEADS);
  float s0 = a_s[jq * 4], s1 = a_s[jq * 4 + 1], s2 = a_s[jq * 4 + 2], s3 = a_s[jq * 4 + 3];
  float d0 = a_d[jq * 4], d1 = a_d[jq * 4 + 1], d2 = a_d[jq * 4 + 2], d3 = a_d[jq * 4 + 3];
  #pragma unroll
  for (int i = 0; i < 4; i++){
    int r = rb + 8 * i, gr = rbase + r;
    if (gr < n){
      __half2 p0 = __floats2half2_rn(acc[i].x, acc[i].y);
      __half2 p1 = __floats2half2_rn(acc[i].z, acc[i].w);
      uint2 pv;
      pv.x = *reinterpret_cast<unsigned int*>(&p0);
      pv.y = *reinterpret_cast<unsigned int*>(&p1);
      *reinterpret_cast<uint2*>(Hh + (size_t)gr * J + jq * 4) = pv;
      float ps = acc[i].x * s0 + acc[i].y * s1 + acc[i].z * s2 + acc[i].w * s3;
      float pd = acc[i].x * d0 + acc[i].y * d1 + acc[i].z * d2 + acc[i].w * d3;
      atomicAdd(&als[r * HEADS + hh], ps);
      atomicAdd(&ald[r * HEADS + hh], pd);
    }
  }
  __syncthreads();
  if (t < ROWS * HEADS){
    int r = t / HEADS, h = t % HEADS, gr = rbase + r;
    if (gr < n){
      asrc[gr * HEADS + h] = als[t];
      adst[gr * HEADS + h] = ald[t];
    }
  }
}

// ---------------- aggregation: wave per dst node, inline edge weights, fp16 gather ----------------
template<int HEADS, int C, bool ELU>
__global__ void agg_k(const __half* __restrict__ Hh,
                      const float* __restrict__ asrc, const float* __restrict__ adst,
                      const int* __restrict__ row_ptr, const int* __restrict__ esrc,
                      const float* __restrict__ bias, float* __restrict__ out, int n){
  constexpr int J = HEADS * C;
  constexpr int NL = J / 2;      // active lanes (each handles a column pair)
  int node = blockIdx.x * (blockDim.x >> 6) + (threadIdx.x >> 6);
  if (node >= n) return;
  int lane = threadIdx.x & 63;
  if (lane >= NL) return;
  int c0 = 2 * lane;
  int hh = c0 / C;
  const __half2* hp = (const __half2*)Hh;

  float ad = adst[node * HEADS + hh];
  float wself = __expf(lrelu(asrc[node * HEADS + hh] + ad));
  float2 hs = __half22float2(hp[(size_t)node * NL + lane]);
  float acc0 = wself * hs.x, acc1 = wself * hs.y, den = wself;

  int beg = row_ptr[node], end = row_ptr[node + 1];
  int e = beg;
  for (; e + 4 <= end; e += 4){
    int s[4]; float w[4]; float2 h[4];
    #pragma unroll
    for (int u = 0; u < 4; u++) s[u] = esrc[e + u];
    #pragma unroll
    for (int u = 0; u < 4; u++) w[u] = __expf(lrelu(asrc[s[u] * HEADS + hh] + ad));
    #pragma unroll
    for (int u = 0; u < 4; u++) h[u] = __half22float2(hp[(size_t)s[u] * NL + lane]);
    #pragma unroll
    for (int u = 0; u < 4; u++){ acc0 += w[u] * h[u].x; acc1 += w[u] * h[u].y; den += w[u]; }
  }
  for (; e < end; e++){
    int s = esrc[e];
    float w = __expf(lrelu(asrc[s * HEADS + hh] + ad));
    float2 h = __half22float2(hp[(size_t)s * NL + lane]);
    acc0 += w * h.x; acc1 += w * h.y; den += w;
  }
  float inv = 1.f / (den + EPS_);
  float r0 = acc0 * inv + bias[c0];
  float r1 = acc1 * inv + bias[c0 + 1];
  if (ELU){
    r0 = r0 > 0.f ? r0 : __expf(r0) - 1.f;
    r1 = r1 > 0.f ? r1 : __expf(r1) - 1.f;
  }
  *reinterpret_cast<float2*>(out + (size_t)node * J + c0) = make_float2(r0, r1);
}

extern "C" void kernel_launch(void* const* d_in, const int* in_sizes, int n_in,
                              void* d_out, int out_size, void* d_ws, size_t ws_size,
                              hipStream_t stream){
  const float* x   = (const float*)d_in[0];
  const int*   ei  = (const int*)  d_in[1];
  const float* W1  = (const float*)d_in[2];
  const float* as1 = (const float*)d_in[3];
  const float* ad1 = (const float*)d_in[4];
  const float* b1  = (const float*)d_in[5];
  const float* W2  = (const float*)d_in[6];
  const float* as2 = (const float*)d_in[7];
  const float* ad2 = (const float*)d_in[8];
  const float* b2  = (const float*)d_in[9];
  const float* W3  = (const float*)d_in[10];
  const float* as3 = (const float*)d_in[11];
  const float* ad3 = (const float*)d_in[12];
  const float* b3  = (const float*)d_in[13];
  float* out = (float*)d_out;

  const int N = N_NODES_C;
  const int E = in_sizes[1] / 2;
  const int* srcv = ei;
  const int* dstv = ei + E;

  char* ws = (char*)d_ws;
  auto alloc = [&](size_t bytes)->char*{ char* p = ws; ws += (bytes + 255) & ~(size_t)255; return p; };
  int*    counts  = (int*)   alloc((size_t)N * 4);
  int*    row_ptr = (int*)   alloc((size_t)(N + 1) * 4);
  int*    fill    = (int*)   alloc((size_t)N * 4);
  int*    csums   = (int*)   alloc(64 * 4);
  int*    coffs   = (int*)   alloc(64 * 4);
  int*    esrc    = (int*)   alloc((size_t)E * 4);
  __half* Hh      = (__half*)alloc((size_t)N * 128 * 2);
  float*  feat    = (float*) alloc((size_t)N * 96 * 4);
  float*  a_src   = (float*) alloc((size_t)N * 3 * 4);
  float*  a_dst   = (float*) alloc((size_t)N * 3 * 4);

  // ---- CSR (by dst), reused by all 3 layers ----
  hipMemsetAsync(counts, 0, (size_t)N * 4, stream);
  hist_k<<<(E + 255) / 256, 256, 0, stream>>>(dstv, counts, E);
  int nch = (N + 1023) / 1024;
  chunksum_k<<<nch, 256, 0, stream>>>(counts, csums, N);
  chunkscan_k<<<1, 64, 0, stream>>>(csums, coffs, row_ptr, nch, N);
  scan_k<<<nch, 1024, 0, stream>>>(counts, coffs, row_ptr, fill, N);
  scatter_k<<<(E + 255) / 256, 256, 0, stream>>>(srcv, dstv, fill, esrc, E);

  int gnode4 = (N + 3) / 4;      // 4 waves (nodes) per 256-thread block
  int grows  = (N + 31) / 32;    // GEMM: 32 rows per block

  // ---- layer 1: 128 -> (3,32), concat, ELU ----
  gemm_alpha_k<128, 96, 3><<<grows, 192, 0, stream>>>(x, W1, as1, ad1, Hh, a_src, a_dst, N);
  agg_k<3, 32, true><<<gnode4, 256, 0, stream>>>(Hh, a_src, a_dst, row_ptr, esrc, b1, feat, N);

  // ---- layer 2: 96 -> (3,32), concat, ELU ----
  gemm_alpha_k<96, 96, 3><<<grows, 192, 0, stream>>>(feat, W2, as2, ad2, Hh, a_src, a_dst, N);
  agg_k<3, 32, true><<<gnode4, 256, 0, stream>>>(Hh, a_src, a_dst, row_ptr, esrc, b2, feat, N);

  // ---- layer 3: 96 -> (1,128), mean(=identity for 1 head), no ELU ----
  gemm_alpha_k<96, 128, 1><<<grows, 256, 0, stream>>>(feat, W3, as3, ad3, Hh, a_src, a_dst, N);
  agg_k<1, 128, false><<<gnode4, 256, 0, stream>>>(Hh, a_src, a_dst, row_ptr, esrc, b3, out, N);
}

// Round 5
// 446.772 us; speedup vs baseline: 1.8933x; 1.0247x over previous
//
#include <hip/hip_runtime.h>
#include <hip/hip_bf16.h>
#include <hip/hip_fp16.h>
#include <math.h>

#define N_NODES_C 50000
#define NEG_SLOPE 0.2f
#define EPS_ 1e-16f

__device__ __forceinline__ float lrelu(float x){ return x > 0.f ? x : NEG_SLOPE * x; }

// ---------------- CSR build ----------------
__global__ void hist_k(const int* __restrict__ dstv, int* __restrict__ counts, int E){
  int t = blockIdx.x * blockDim.x + threadIdx.x;
  if (t < E) atomicAdd(&counts[dstv[t]], 1);
}

__global__ void chunksum_k(const int* __restrict__ counts, int* __restrict__ sums, int n){
  __shared__ int lds[4];
  int base = blockIdx.x * 1024;
  int t = threadIdx.x; // 256
  int s = 0;
  for (int i = t; i < 1024; i += 256){ int idx = base + i; s += (idx < n) ? counts[idx] : 0; }
  for (int d = 32; d >= 1; d >>= 1) s += __shfl_xor(s, d);
  if ((t & 63) == 0) lds[t >> 6] = s;
  __syncthreads();
  if (t == 0) sums[blockIdx.x] = lds[0] + lds[1] + lds[2] + lds[3];
}

__global__ void chunkscan_k(const int* __restrict__ sums, int* __restrict__ offs,
                            int* __restrict__ row_ptr, int nblocks, int n){
  int l = threadIdx.x; // 64
  int v = (l < nblocks) ? sums[l] : 0;
  int x = v;
  for (int d = 1; d < 64; d <<= 1){ int y = __shfl_up(x, d); if (l >= d) x += y; }
  if (l < nblocks) offs[l] = x - v;
  if (l == nblocks - 1) row_ptr[n] = x;
}

__global__ void scan_k(const int* __restrict__ counts, const int* __restrict__ offs,
                       int* __restrict__ row_ptr, int* __restrict__ fill, int n){
  __shared__ int ws[16];
  int base = blockIdx.x * 1024; int t = threadIdx.x; int idx = base + t;
  int v = (idx < n) ? counts[idx] : 0;
  int lane = t & 63, wid = t >> 6;
  int x = v;
  for (int d = 1; d < 64; d <<= 1){ int y = __shfl_up(x, d); if (lane >= d) x += y; }
  if (lane == 63) ws[wid] = x;
  __syncthreads();
  if (t < 16){ int y = ws[t]; for (int d = 1; d < 16; d <<= 1){ int z = __shfl_up(y, d); if (t >= d) y += z; } ws[t] = y; }
  __syncthreads();
  int excl = x - v + (wid ? ws[wid - 1] : 0) + offs[blockIdx.x];
  if (idx < n){ row_ptr[idx] = excl; fill[idx] = excl; }
}

__global__ void scatter_k(const int* __restrict__ srcv, const int* __restrict__ dstv,
                          int* __restrict__ fill, int* __restrict__ esrc, int E){
  int t = blockIdx.x * blockDim.x + threadIdx.x;
  if (t < E){ int p = atomicAdd(&fill[dstv[t]], 1); esrc[p] = srcv[t]; }
}

// ---------------- fused GEMM + alpha: H(fp16)[n][J] = A[n][K] @ W[K][J]; alpha = H·a ----------------
// W is read straight from global (L1/L2-resident, wave-broadcast); only the A-tile is LDS-staged.
template<int K, int J, int HEADS>
__global__ __launch_bounds__((J/4)*8) void gemm_alpha_k(
    const float* __restrict__ A, const float* __restrict__ W,
    const float* __restrict__ a_s, const float* __restrict__ a_d,
    __half* __restrict__ Hh, float* __restrict__ asrc, float* __restrict__ adst, int n){
  constexpr int NQ = J / 4;       // col quads
  constexpr int NT = NQ * 8;      // threads
  constexpr int ROWS = 32;
  constexpr int KQ = K / 4;
  constexpr int KQP = KQ + 1;     // padded (in float4 units)
  __shared__ float4 Al[ROWS * KQP];
  __shared__ float  als[ROWS * HEADS];
  __shared__ float  ald[ROWS * HEADS];
  int t = threadIdx.x;
  int rbase = blockIdx.x * ROWS;
  for (int i = t; i < ROWS * KQ; i += NT){
    int r = i / KQ, kq = i % KQ;
    float4 v = make_float4(0.f, 0.f, 0.f, 0.f);
    if (rbase + r < n) v = ((const float4*)(A + (size_t)(rbase + r) * K))[kq];
    Al[r * KQP + kq] = v;
  }
  if (t < ROWS * HEADS){ als[t] = 0.f; ald[t] = 0.f; }
  __syncthreads();
  int jq = t % NQ; int rb = t / NQ; // rb in 0..7
  const float4* Wg = (const float4*)W;  // W[K][J] as rows of float4
  float4 acc[4];
  #pragma unroll
  for (int i = 0; i < 4; i++) acc[i] = make_float4(0.f, 0.f, 0.f, 0.f);
  float4 w0 = Wg[0 * NQ + jq];
  float4 w1 = Wg[1 * NQ + jq];
  float4 w2 = Wg[2 * NQ + jq];
  float4 w3 = Wg[3 * NQ + jq];
  for (int kb = 0; kb < KQ; kb++){
    int kn = (kb + 1 < KQ) ? (kb + 1) : kb;   // clamped prefetch
    float4 nw0 = Wg[(4 * kn + 0) * NQ + jq];
    float4 nw1 = Wg[(4 * kn + 1) * NQ + jq];
    float4 nw2 = Wg[(4 * kn + 2) * NQ + jq];
    float4 nw3 = Wg[(4 * kn + 3) * NQ + jq];
    #pragma unroll
    for (int i = 0; i < 4; i++){
      float4 a = Al[(rb + 8 * i) * KQP + kb];
      acc[i].x += a.x * w0.x + a.y * w1.x + a.z * w2.x + a.w * w3.x;
      acc[i].y += a.x * w0.y + a.y * w1.y + a.z * w2.y + a.w * w3.y;
      acc[i].z += a.x * w0.z + a.y * w1.z + a.z * w2.z + a.w * w3.z;
      acc[i].w += a.x * w0.w + a.y * w1.w + a.z * w2.w + a.w * w3.w;
    }
    w0 = nw0; w1 = nw1; w2 = nw2; w3 = nw3;
  }
  // epilogue: fp16 store + per-head alpha partial reduction
  int hh = (jq * 4) / (J / HEADS);
  float s0 = a_s[jq * 4], s1 = a_s[jq * 4 + 1], s2 = a_s[jq * 4 + 2], s3 = a_s[jq * 4 + 3];
  float d0 = a_d[jq * 4], d1 = a_d[jq * 4 + 1], d2 = a_d[jq * 4 + 2], d3 = a_d[jq * 4 + 3];
  #pragma unroll
  for (int i = 0; i < 4; i++){
    int r = rb + 8 * i, gr = rbase + r;
    if (gr < n){
      __half2 p0 = __floats2half2_rn(acc[i].x, acc[i].y);
      __half2 p1 = __floats2half2_rn(acc[i].z, acc[i].w);
      uint2 pv;
      pv.x = *reinterpret_cast<unsigned int*>(&p0);
      pv.y = *reinterpret_cast<unsigned int*>(&p1);
      *reinterpret_cast<uint2*>(Hh + (size_t)gr * J + jq * 4) = pv;
      float ps = acc[i].x * s0 + acc[i].y * s1 + acc[i].z * s2 + acc[i].w * s3;
      float pd = acc[i].x * d0 + acc[i].y * d1 + acc[i].z * d2 + acc[i].w * d3;
      atomicAdd(&als[r * HEADS + hh], ps);
      atomicAdd(&ald[r * HEADS + hh], pd);
    }
  }
  __syncthreads();
  if (t < ROWS * HEADS){
    int r = t / HEADS, h = t % HEADS, gr = rbase + r;
    if (gr < n){
      asrc[gr * HEADS + h] = als[t];
      adst[gr * HEADS + h] = ald[t];
    }
  }
}

// ---------------- aggregation: wave per dst node, inline edge weights, fp16 gather ----------------
template<int HEADS, int C, bool ELU>
__global__ void agg_k(const __half* __restrict__ Hh,
                      const float* __restrict__ asrc, const float* __restrict__ adst,
                      const int* __restrict__ row_ptr, const int* __restrict__ esrc,
                      const float* __restrict__ bias, float* __restrict__ out, int n){
  constexpr int J = HEADS * C;
  constexpr int NL = J / 2;      // active lanes (each handles a column pair)
  int node = blockIdx.x * (blockDim.x >> 6) + (threadIdx.x >> 6);
  if (node >= n) return;
  int lane = threadIdx.x & 63;
  if (lane >= NL) return;
  int c0 = 2 * lane;
  int hh = c0 / C;
  const __half2* hp = (const __half2*)Hh;

  float ad = adst[node * HEADS + hh];
  float wself = __expf(lrelu(asrc[node * HEADS + hh] + ad));
  float2 hs = __half22float2(hp[(size_t)node * NL + lane]);
  float acc0 = wself * hs.x, acc1 = wself * hs.y, den = wself;

  int beg = row_ptr[node], end = row_ptr[node + 1];
  int e = beg;
  for (; e + 4 <= end; e += 4){
    int s[4]; float w[4]; float2 h[4];
    #pragma unroll
    for (int u = 0; u < 4; u++) s[u] = esrc[e + u];
    #pragma unroll
    for (int u = 0; u < 4; u++) w[u] = __expf(lrelu(asrc[s[u] * HEADS + hh] + ad));
    #pragma unroll
    for (int u = 0; u < 4; u++) h[u] = __half22float2(hp[(size_t)s[u] * NL + lane]);
    #pragma unroll
    for (int u = 0; u < 4; u++){ acc0 += w[u] * h[u].x; acc1 += w[u] * h[u].y; den += w[u]; }
  }
  for (; e < end; e++){
    int s = esrc[e];
    float w = __expf(lrelu(asrc[s * HEADS + hh] + ad));
    float2 h = __half22float2(hp[(size_t)s * NL + lane]);
    acc0 += w * h.x; acc1 += w * h.y; den += w;
  }
  float inv = 1.f / (den + EPS_);
  float r0 = acc0 * inv + bias[c0];
  float r1 = acc1 * inv + bias[c0 + 1];
  if (ELU){
    r0 = r0 > 0.f ? r0 : __expf(r0) - 1.f;
    r1 = r1 > 0.f ? r1 : __expf(r1) - 1.f;
  }
  *reinterpret_cast<float2*>(out + (size_t)node * J + c0) = make_float2(r0, r1);
}

extern "C" void kernel_launch(void* const* d_in, const int* in_sizes, int n_in,
                              void* d_out, int out_size, void* d_ws, size_t ws_size,
                              hipStream_t stream){
  const float* x   = (const float*)d_in[0];
  const int*   ei  = (const int*)  d_in[1];
  const float* W1  = (const float*)d_in[2];
  const float* as1 = (const float*)d_in[3];
  const float* ad1 = (const float*)d_in[4];
  const float* b1  = (const float*)d_in[5];
  const float* W2  = (const float*)d_in[6];
  const float* as2 = (const float*)d_in[7];
  const float* ad2 = (const float*)d_in[8];
  const float* b2  = (const float*)d_in[9];
  const float* W3  = (const float*)d_in[10];
  const float* as3 = (const float*)d_in[11];
  const float* ad3 = (const float*)d_in[12];
  const float* b3  = (const float*)d_in[13];
  float* out = (float*)d_out;

  const int N = N_NODES_C;
  const int E = in_sizes[1] / 2;
  const int* srcv = ei;
  const int* dstv = ei + E;

  char* ws = (char*)d_ws;
  auto alloc = [&](size_t bytes)->char*{ char* p = ws; ws += (bytes + 255) & ~(size_t)255; return p; };
  int*    counts  = (int*)   alloc((size_t)N * 4);
  int*    row_ptr = (int*)   alloc((size_t)(N + 1) * 4);
  int*    fill    = (int*)   alloc((size_t)N * 4);
  int*    csums   = (int*)   alloc(64 * 4);
  int*    coffs   = (int*)   alloc(64 * 4);
  int*    esrc    = (int*)   alloc((size_t)E * 4);
  __half* Hh      = (__half*)alloc((size_t)N * 128 * 2);
  float*  feat    = (float*) alloc((size_t)N * 96 * 4);
  float*  a_src   = (float*) alloc((size_t)N * 3 * 4);
  float*  a_dst   = (float*) alloc((size_t)N * 3 * 4);

  // ---- CSR (by dst), reused by all 3 layers ----
  hipMemsetAsync(counts, 0, (size_t)N * 4, stream);
  hist_k<<<(E + 255) / 256, 256, 0, stream>>>(dstv, counts, E);
  int nch = (N + 1023) / 1024;
  chunksum_k<<<nch, 256, 0, stream>>>(counts, csums, N);
  chunkscan_k<<<1, 64, 0, stream>>>(csums, coffs, row_ptr, nch, N);
  scan_k<<<nch, 1024, 0, stream>>>(counts, coffs, row_ptr, fill, N);
  scatter_k<<<(E + 255) / 256, 256, 0, stream>>>(srcv, dstv, fill, esrc, E);

  int gnode4 = (N + 3) / 4;      // 4 waves (nodes) per 256-thread block
  int grows  = (N + 31) / 32;    // GEMM: 32 rows per block

  // ---- layer 1: 128 -> (3,32), concat, ELU ----
  gemm_alpha_k<128, 96, 3><<<grows, 192, 0, stream>>>(x, W1, as1, ad1, Hh, a_src, a_dst, N);
  agg_k<3, 32, true><<<gnode4, 256, 0, stream>>>(Hh, a_src, a_dst, row_ptr, esrc, b1, feat, N);

  // ---- layer 2: 96 -> (3,32), concat, ELU ----
  gemm_alpha_k<96, 96, 3><<<grows, 192, 0, stream>>>(feat, W2, as2, ad2, Hh, a_src, a_dst, N);
  agg_k<3, 32, true><<<gnode4, 256, 0, stream>>>(Hh, a_src, a_dst, row_ptr, esrc, b2, feat, N);

  // ---- layer 3: 96 -> (1,128), mean(=identity for 1 head), no ELU ----
  gemm_alpha_k<96, 128, 1><<<grows, 256, 0, stream>>>(feat, W3, as3, ad3, Hh, a_src, a_dst, N);
  agg_k<1, 128, false><<<gnode4, 256, 0, stream>>>(Hh, a_src, a_dst, row_ptr, esrc, b3, out, N);
}

// Round 6
// 361.323 us; speedup vs baseline: 2.3410x; 1.2365x over previous
//
#include <hip/hip_runtime.h>
#include <hip/hip_bf16.h>
#include <hip/hip_fp16.h>
#include <math.h>

#define N_NODES_C 50000
#define NEG_SLOPE 0.2f
#define EPS_ 1e-16f

typedef _Float16 f16x8 __attribute__((ext_vector_type(8)));
typedef float    f32x4 __attribute__((ext_vector_type(4)));

__device__ __forceinline__ float lrelu(float x){ return x > 0.f ? x : NEG_SLOPE * x; }

// ---------------- CSR build ----------------
__global__ void hist_k(const int* __restrict__ dstv, int* __restrict__ counts, int E){
  int t = blockIdx.x * blockDim.x + threadIdx.x;
  if (t < E) atomicAdd(&counts[dstv[t]], 1);
}

__global__ void chunksum_k(const int* __restrict__ counts, int* __restrict__ sums, int n){
  __shared__ int lds[4];
  int base = blockIdx.x * 1024;
  int t = threadIdx.x; // 256
  int s = 0;
  for (int i = t; i < 1024; i += 256){ int idx = base + i; s += (idx < n) ? counts[idx] : 0; }
  for (int d = 32; d >= 1; d >>= 1) s += __shfl_xor(s, d);
  if ((t & 63) == 0) lds[t >> 6] = s;
  __syncthreads();
  if (t == 0) sums[blockIdx.x] = lds[0] + lds[1] + lds[2] + lds[3];
}

__global__ void chunkscan_k(const int* __restrict__ sums, int* __restrict__ offs,
                            int* __restrict__ row_ptr, int nblocks, int n){
  int l = threadIdx.x; // 64
  int v = (l < nblocks) ? sums[l] : 0;
  int x = v;
  for (int d = 1; d < 64; d <<= 1){ int y = __shfl_up(x, d); if (l >= d) x += y; }
  if (l < nblocks) offs[l] = x - v;
  if (l == nblocks - 1) row_ptr[n] = x;
}

__global__ void scan_k(const int* __restrict__ counts, const int* __restrict__ offs,
                       int* __restrict__ row_ptr, int* __restrict__ fill, int n){
  __shared__ int ws[16];
  int base = blockIdx.x * 1024; int t = threadIdx.x; int idx = base + t;
  int v = (idx < n) ? counts[idx] : 0;
  int lane = t & 63, wid = t >> 6;
  int x = v;
  for (int d = 1; d < 64; d <<= 1){ int y = __shfl_up(x, d); if (lane >= d) x += y; }
  if (lane == 63) ws[wid] = x;
  __syncthreads();
  if (t < 16){ int y = ws[t]; for (int d = 1; d < 16; d <<= 1){ int z = __shfl_up(y, d); if (t >= d) y += z; } ws[t] = y; }
  __syncthreads();
  int excl = x - v + (wid ? ws[wid - 1] : 0) + offs[blockIdx.x];
  if (idx < n){ row_ptr[idx] = excl; fill[idx] = excl; }
}

__global__ void scatter_k(const int* __restrict__ srcv, const int* __restrict__ dstv,
                          int* __restrict__ fill, int* __restrict__ esrc, int E){
  int t = blockIdx.x * blockDim.x + threadIdx.x;
  if (t < E){ int p = atomicAdd(&fill[dstv[t]], 1); esrc[p] = srcv[t]; }
}

// ---------------- W repack to MFMA B-fragment order (fp16) ----------------
// Wf[((kk*NT + nt)*64 + lane)] = uint4 of 8 halfs: B[kk*32 + (lane>>4)*8 + j][nt*16 + (lane&15)]
template<int K, int J>
__global__ void wpack_k(const float* __restrict__ W, uint4* __restrict__ Wf){
  constexpr int KS = K / 32, NT = J / 16;
  int tot = KS * NT * 64;
  for (int t = blockIdx.x * blockDim.x + threadIdx.x; t < tot; t += gridDim.x * blockDim.x){
    int l = t & 63;
    int nt = (t >> 6) % NT;
    int kk = t / (64 * NT);
    int col = nt * 16 + (l & 15);
    int k0 = kk * 32 + (l >> 4) * 8;
    unsigned u[4];
    #pragma unroll
    for (int p = 0; p < 4; p++){
      __half2 h = __floats2half2_rn(W[(k0 + 2 * p) * J + col], W[(k0 + 2 * p + 1) * J + col]);
      u[p] = *reinterpret_cast<unsigned*>(&h);
    }
    uint4 v; v.x = u[0]; v.y = u[1]; v.z = u[2]; v.w = u[3];
    Wf[t] = v;
  }
}

// ---------------- MFMA GEMM + alpha: Hh(fp16)[n][J] = A[n][K] @ W[K][J]; alpha = acc·a ----------------
// 256 threads = 4 waves; 64 rows/block; wave w owns rows w*16..w*16+15, all J cols.
template<int K, int J, int HEADS, bool AF16>
__global__ __launch_bounds__(256) void gemm_mfma_k(
    const void* __restrict__ Ain, const uint4* __restrict__ Wf,
    const float* __restrict__ a_s, const float* __restrict__ a_d,
    __half* __restrict__ Hh, float* __restrict__ asrc, float* __restrict__ adst, int n){
  constexpr int KS = K / 32;        // k-steps
  constexpr int NT = J / 16;        // n-tiles
  constexpr int CPR = K / 8;        // 16B chunks per row
  constexpr int NTPH = NT / HEADS;  // n-tiles per head
  __shared__ uint4 Alds[64 * 16];   // 16KB, row stride fixed at 16 chunks, XOR-swizzled
  int t = threadIdx.x;
  int rbase = blockIdx.x * 64;

  // stage A tile (fp16, swizzled)
  for (int i = t; i < 64 * CPR; i += 256){
    int r = i / CPR, c = i % CPR;
    int gr = rbase + r;
    uint4 v = make_uint4(0u, 0u, 0u, 0u);
    if (gr < n){
      if (AF16){
        v = ((const uint4*)Ain)[(size_t)gr * CPR + c];
      } else {
        const float4* af = (const float4*)Ain + (size_t)gr * (K / 4) + c * 2;
        float4 lo = af[0], hi = af[1];
        __half2 p0 = __floats2half2_rn(lo.x, lo.y);
        __half2 p1 = __floats2half2_rn(lo.z, lo.w);
        __half2 p2 = __floats2half2_rn(hi.x, hi.y);
        __half2 p3 = __floats2half2_rn(hi.z, hi.w);
        v.x = *reinterpret_cast<unsigned*>(&p0);
        v.y = *reinterpret_cast<unsigned*>(&p1);
        v.z = *reinterpret_cast<unsigned*>(&p2);
        v.w = *reinterpret_cast<unsigned*>(&p3);
      }
    }
    Alds[r * 16 + (c ^ (r & 7))] = v;
  }
  __syncthreads();

  int l = t & 63;
  int wrow = (t >> 6) * 16;         // wave's row-tile base
  int sub = l & 15;                 // col-in-tile / row-in-tile
  int lk = l >> 4;                  // k-subgroup
  f32x4 acc[NT];
  #pragma unroll
  for (int i = 0; i < NT; i++) acc[i] = (f32x4){0.f, 0.f, 0.f, 0.f};

  for (int kk = 0; kk < KS; kk++){
    int trow = wrow + sub;
    int c = kk * 4 + lk;
    f16x8 a = *reinterpret_cast<const f16x8*>(&Alds[trow * 16 + (c ^ (trow & 7))]);
    const uint4* wb = Wf + (size_t)(kk * NT) * 64 + l;
    #pragma unroll
    for (int nt = 0; nt < NT; nt++){
      uint4 wv = wb[nt * 64];
      f16x8 b = *reinterpret_cast<const f16x8*>(&wv);
      acc[nt] = __builtin_amdgcn_mfma_f32_16x16x32_f16(a, b, acc[nt], 0, 0, 0);
    }
  }

  // epilogue: C/D layout col = nt*16 + sub, row (in tile) = lk*4 + r
  // alpha partials per head, per reg-row
  float ps[HEADS][4], pd[HEADS][4];
  #pragma unroll
  for (int h = 0; h < HEADS; h++)
    #pragma unroll
    for (int r = 0; r < 4; r++){ ps[h][r] = 0.f; pd[h][r] = 0.f; }
  #pragma unroll
  for (int nt = 0; nt < NT; nt++){
    int h = nt / NTPH;
    float sa = a_s[nt * 16 + sub];
    float sd = a_d[nt * 16 + sub];
    #pragma unroll
    for (int r = 0; r < 4; r++){ ps[h][r] += acc[nt][r] * sa; pd[h][r] += acc[nt][r] * sd; }
  }
  #pragma unroll
  for (int h = 0; h < HEADS; h++)
    #pragma unroll
    for (int r = 0; r < 4; r++)
      #pragma unroll
      for (int d = 1; d < 16; d <<= 1){
        ps[h][r] += __shfl_xor(ps[h][r], d);
        pd[h][r] += __shfl_xor(pd[h][r], d);
      }

  // Hh store (fp16 scalar stores; 16 lanes cover 32 contiguous bytes)
  #pragma unroll
  for (int r = 0; r < 4; r++){
    int gr = rbase + wrow + lk * 4 + r;
    if (gr < n){
      #pragma unroll
      for (int nt = 0; nt < NT; nt++)
        Hh[(size_t)gr * J + nt * 16 + sub] = __float2half(acc[nt][r]);
    }
  }
  // alpha store: lane with sub==h writes head h
  #pragma unroll
  for (int h = 0; h < HEADS; h++){
    if (sub == h){
      #pragma unroll
      for (int r = 0; r < 4; r++){
        int gr = rbase + wrow + lk * 4 + r;
        if (gr < n){
          asrc[gr * HEADS + h] = ps[h][r];
          adst[gr * HEADS + h] = pd[h][r];
        }
      }
    }
  }
}

// ---------------- aggregation: wave per dst node, inline edge weights, fp16 gather ----------------
template<int HEADS, int C, bool ELU, bool OUT16>
__global__ void agg_k(const __half* __restrict__ Hh,
                      const float* __restrict__ asrc, const float* __restrict__ adst,
                      const int* __restrict__ row_ptr, const int* __restrict__ esrc,
                      const float* __restrict__ bias, void* __restrict__ outv, int n){
  constexpr int J = HEADS * C;
  constexpr int NL = J / 2;      // active lanes (each handles a column pair)
  int node = blockIdx.x * (blockDim.x >> 6) + (threadIdx.x >> 6);
  if (node >= n) return;
  int lane = threadIdx.x & 63;
  if (lane >= NL) return;
  int c0 = 2 * lane;
  int hh = c0 / C;
  const __half2* hp = (const __half2*)Hh;

  float ad = adst[node * HEADS + hh];
  float wself = __expf(lrelu(asrc[node * HEADS + hh] + ad));
  float2 hs = __half22float2(hp[(size_t)node * NL + lane]);
  float acc0 = wself * hs.x, acc1 = wself * hs.y, den = wself;

  int beg = row_ptr[node], end = row_ptr[node + 1];
  int e = beg;
  for (; e + 4 <= end; e += 4){
    int s[4]; float w[4]; float2 h[4];
    #pragma unroll
    for (int u = 0; u < 4; u++) s[u] = esrc[e + u];
    #pragma unroll
    for (int u = 0; u < 4; u++) w[u] = __expf(lrelu(asrc[s[u] * HEADS + hh] + ad));
    #pragma unroll
    for (int u = 0; u < 4; u++) h[u] = __half22float2(hp[(size_t)s[u] * NL + lane]);
    #pragma unroll
    for (int u = 0; u < 4; u++){ acc0 += w[u] * h[u].x; acc1 += w[u] * h[u].y; den += w[u]; }
  }
  for (; e < end; e++){
    int s = esrc[e];
    float w = __expf(lrelu(asrc[s * HEADS + hh] + ad));
    float2 h = __half22float2(hp[(size_t)s * NL + lane]);
    acc0 += w * h.x; acc1 += w * h.y; den += w;
  }
  float inv = 1.f / (den + EPS_);
  float r0 = acc0 * inv + bias[c0];
  float r1 = acc1 * inv + bias[c0 + 1];
  if (ELU){
    r0 = r0 > 0.f ? r0 : __expf(r0) - 1.f;
    r1 = r1 > 0.f ? r1 : __expf(r1) - 1.f;
  }
  if (OUT16){
    ((__half2*)outv)[(size_t)node * NL + lane] = __floats2half2_rn(r0, r1);
  } else {
    *reinterpret_cast<float2*>((float*)outv + (size_t)node * J + c0) = make_float2(r0, r1);
  }
}

extern "C" void kernel_launch(void* const* d_in, const int* in_sizes, int n_in,
                              void* d_out, int out_size, void* d_ws, size_t ws_size,
                              hipStream_t stream){
  const float* x   = (const float*)d_in[0];
  const int*   ei  = (const int*)  d_in[1];
  const float* W1  = (const float*)d_in[2];
  const float* as1 = (const float*)d_in[3];
  const float* ad1 = (const float*)d_in[4];
  const float* b1  = (const float*)d_in[5];
  const float* W2  = (const float*)d_in[6];
  const float* as2 = (const float*)d_in[7];
  const float* ad2 = (const float*)d_in[8];
  const float* b2  = (const float*)d_in[9];
  const float* W3  = (const float*)d_in[10];
  const float* as3 = (const float*)d_in[11];
  const float* ad3 = (const float*)d_in[12];
  const float* b3  = (const float*)d_in[13];
  float* out = (float*)d_out;

  const int N = N_NODES_C;
  const int E = in_sizes[1] / 2;
  const int* srcv = ei;
  const int* dstv = ei + E;

  char* ws = (char*)d_ws;
  auto alloc = [&](size_t bytes)->char*{ char* p = ws; ws += (bytes + 255) & ~(size_t)255; return p; };
  int*    counts  = (int*)   alloc((size_t)N * 4);
  int*    row_ptr = (int*)   alloc((size_t)(N + 1) * 4);
  int*    fill    = (int*)   alloc((size_t)N * 4);
  int*    csums   = (int*)   alloc(64 * 4);
  int*    coffs   = (int*)   alloc(64 * 4);
  int*    esrc    = (int*)   alloc((size_t)E * 4);
  __half* Hh      = (__half*)alloc((size_t)N * 128 * 2);
  __half* feat_h  = (__half*)alloc((size_t)N * 96 * 2);
  float*  a_src   = (float*) alloc((size_t)N * 3 * 4);
  float*  a_dst   = (float*) alloc((size_t)N * 3 * 4);
  uint4*  Wf1     = (uint4*) alloc(128 * 96 * 2);
  uint4*  Wf2     = (uint4*) alloc(96 * 96 * 2);
  uint4*  Wf3     = (uint4*) alloc(96 * 128 * 2);

  // ---- CSR (by dst), reused by all 3 layers ----
  hipMemsetAsync(counts, 0, (size_t)N * 4, stream);
  hist_k<<<(E + 255) / 256, 256, 0, stream>>>(dstv, counts, E);
  int nch = (N + 1023) / 1024;
  chunksum_k<<<nch, 256, 0, stream>>>(counts, csums, N);
  chunkscan_k<<<1, 64, 0, stream>>>(csums, coffs, row_ptr, nch, N);
  scan_k<<<nch, 1024, 0, stream>>>(counts, coffs, row_ptr, fill, N);
  scatter_k<<<(E + 255) / 256, 256, 0, stream>>>(srcv, dstv, fill, esrc, E);

  // ---- W repacks (tiny) ----
  wpack_k<128, 96><<<6, 256, 0, stream>>>(W1, Wf1);
  wpack_k<96, 96><<<5, 256, 0, stream>>>(W2, Wf2);
  wpack_k<96, 128><<<6, 256, 0, stream>>>(W3, Wf3);

  int gnode4 = (N + 3) / 4;      // 4 waves (nodes) per 256-thread block
  int ggemm  = (N + 63) / 64;    // 64 rows per block

  // ---- layer 1: 128 -> (3,32), concat, ELU ----
  gemm_mfma_k<128, 96, 3, false><<<ggemm, 256, 0, stream>>>(x, Wf1, as1, ad1, Hh, a_src, a_dst, N);
  agg_k<3, 32, true, true><<<gnode4, 256, 0, stream>>>(Hh, a_src, a_dst, row_ptr, esrc, b1, feat_h, N);

  // ---- layer 2: 96 -> (3,32), concat, ELU ----
  gemm_mfma_k<96, 96, 3, true><<<ggemm, 256, 0, stream>>>(feat_h, Wf2, as2, ad2, Hh, a_src, a_dst, N);
  agg_k<3, 32, true, true><<<gnode4, 256, 0, stream>>>(Hh, a_src, a_dst, row_ptr, esrc, b2, feat_h, N);

  // ---- layer 3: 96 -> (1,128), mean(=identity for 1 head), no ELU ----
  gemm_mfma_k<96, 128, 1, true><<<ggemm, 256, 0, stream>>>(feat_h, Wf3, as3, ad3, Hh, a_src, a_dst, N);
  agg_k<1, 128, false, false><<<gnode4, 256, 0, stream>>>(Hh, a_src, a_dst, row_ptr, esrc, b3, out, N);
}

// Round 9
// 335.253 us; speedup vs baseline: 2.5230x; 1.0778x over previous
//
#include <hip/hip_runtime.h>
#include <hip/hip_bf16.h>
#include <hip/hip_fp16.h>
#include <math.h>

#define N_NODES_C 50000
#define NBKT ((N_NODES_C + 255) / 256)   // 196 buckets of 256 nodes
#define NEG_SLOPE 0.2f
#define EPS_ 1e-16f

typedef _Float16 f16x8 __attribute__((ext_vector_type(8)));
typedef float    f32x4 __attribute__((ext_vector_type(4)));

__device__ __forceinline__ float lrelu(float x){ return x > 0.f ? x : NEG_SLOPE * x; }

// ---------------- CSR build ----------------
__global__ void hist_k(const int* __restrict__ dstv, int* __restrict__ counts, int E){
  int t = blockIdx.x * blockDim.x + threadIdx.x;
  if (t < E) atomicAdd(&counts[dstv[t]], 1);
}

__global__ void chunksum_k(const int* __restrict__ counts, int* __restrict__ sums, int n){
  __shared__ int lds[4];
  int base = blockIdx.x * 1024;
  int t = threadIdx.x; // 256
  int s = 0;
  for (int i = t; i < 1024; i += 256){ int idx = base + i; s += (idx < n) ? counts[idx] : 0; }
  for (int d = 32; d >= 1; d >>= 1) s += __shfl_xor(s, d);
  if ((t & 63) == 0) lds[t >> 6] = s;
  __syncthreads();
  if (t == 0) sums[blockIdx.x] = lds[0] + lds[1] + lds[2] + lds[3];
}

__global__ void chunkscan_k(const int* __restrict__ sums, int* __restrict__ offs,
                            int* __restrict__ row_ptr, int nblocks, int n){
  int l = threadIdx.x; // 64
  int v = (l < nblocks) ? sums[l] : 0;
  int x = v;
  for (int d = 1; d < 64; d <<= 1){ int y = __shfl_up(x, d); if (l >= d) x += y; }
  if (l < nblocks) offs[l] = x - v;
  if (l == nblocks - 1) row_ptr[n] = x;
}

__global__ void scan_k(const int* __restrict__ counts, const int* __restrict__ offs,
                       int* __restrict__ row_ptr, int* __restrict__ fill, int n){
  __shared__ int ws[16];
  int base = blockIdx.x * 1024; int t = threadIdx.x; int idx = base + t;
  int v = (idx < n) ? counts[idx] : 0;
  int lane = t & 63, wid = t >> 6;
  int x = v;
  for (int d = 1; d < 64; d <<= 1){ int y = __shfl_up(x, d); if (lane >= d) x += y; }
  if (lane == 63) ws[wid] = x;
  __syncthreads();
  if (t < 16){ int y = ws[t]; for (int d = 1; d < 16; d <<= 1){ int z = __shfl_up(y, d); if (t >= d) y += z; } ws[t] = y; }
  __syncthreads();
  int excl = x - v + (wid ? ws[wid - 1] : 0) + offs[blockIdx.x];
  if (idx < n){ row_ptr[idx] = excl; fill[idx] = excl; }
}

// bucket cursors: bcur[b] = row_ptr[b*256]
__global__ void binit_k(const int* __restrict__ row_ptr, int* __restrict__ bcur){
  int b = blockIdx.x * blockDim.x + threadIdx.x;
  if (b < NBKT) bcur[b] = row_ptr[b * 256];
}

// phase 1: classify edges into 196 dst-buckets with LDS staging, contiguous flushes.
// entry = src | (dst & 255) << 16   (src < 65536, dst-low 8 bits)
#define BATCH 2048
#define BCAP 32
__global__ __launch_bounds__(256) void bucket_k(const int* __restrict__ srcv, const int* __restrict__ dstv,
                                                int* __restrict__ bcur, unsigned* __restrict__ ebuf, int E){
  __shared__ unsigned stage[NBKT * BCAP];   // 25 KB
  __shared__ int cnt[NBKT];
  int t = threadIdx.x;
  int start = blockIdx.x * BATCH;
  int end = start + BATCH; if (end > E) end = E;
  for (int i = t; i < NBKT; i += 256) cnt[i] = 0;
  __syncthreads();
  for (int e = start + t; e < end; e += 256){
    int s = srcv[e], d = dstv[e];
    int b = d >> 8;
    unsigned entry = (unsigned)s | ((unsigned)(d & 255) << 16);
    int pos = atomicAdd(&cnt[b], 1);
    if (pos < BCAP) stage[b * BCAP + pos] = entry;
    else { int p = atomicAdd(&bcur[b], 1); ebuf[p] = entry; }   // rare overflow
  }
  __syncthreads();
  if (t < NBKT){
    int c = cnt[t]; if (c > BCAP) c = BCAP;
    if (c > 0){
      int p = atomicAdd(&bcur[t], c);
      for (int i = 0; i < c; i++) ebuf[p + i] = stage[t * BCAP + i];
    }
  }
}

// phase 2: one block owns one bucket; rank edges per node via LDS counters,
// scatter confined to the block's own 16KB esrc window (L2-absorbed).
__global__ __launch_bounds__(256) void bsort_k(const unsigned* __restrict__ ebuf,
                                               const int* __restrict__ row_ptr,
                                               int* __restrict__ esrc, int n){
  __shared__ int cnt[256];
  int b = blockIdx.x;
  int nb = b * 256;
  int t = threadIdx.x;
  cnt[t] = 0;
  __syncthreads();
  int hi_node = nb + 256; if (hi_node > n) hi_node = n;
  int beg = row_ptr[nb], end = row_ptr[hi_node];
  for (int i = beg + t; i < end; i += 256){
    unsigned e = ebuf[i];
    int dl = e >> 16;
    int src = (int)(e & 0xFFFFu);
    int rank = atomicAdd(&cnt[dl], 1);
    esrc[row_ptr[nb + dl] + rank] = src;
  }
}

// ---------------- W repack to MFMA B-fragment order (fp16) ----------------
template<int K, int J>
__global__ void wpack_k(const float* __restrict__ W, uint4* __restrict__ Wf){
  constexpr int KS = K / 32, NT = J / 16;
  int tot = KS * NT * 64;
  for (int t = blockIdx.x * blockDim.x + threadIdx.x; t < tot; t += gridDim.x * blockDim.x){
    int l = t & 63;
    int nt = (t >> 6) % NT;
    int kk = t / (64 * NT);
    int col = nt * 16 + (l & 15);
    int k0 = kk * 32 + (l >> 4) * 8;
    unsigned u[4];
    #pragma unroll
    for (int p = 0; p < 4; p++){
      __half2 h = __floats2half2_rn(W[(k0 + 2 * p) * J + col], W[(k0 + 2 * p + 1) * J + col]);
      u[p] = *reinterpret_cast<unsigned*>(&h);
    }
    uint4 v; v.x = u[0]; v.y = u[1]; v.z = u[2]; v.w = u[3];
    Wf[t] = v;
  }
}

// ---------------- MFMA GEMM + alpha ----------------
template<int K, int J, int HEADS, bool AF16>
__global__ __launch_bounds__(256) void gemm_mfma_k(
    const void* __restrict__ Ain, const uint4* __restrict__ Wf,
    const float* __restrict__ a_s, const float* __restrict__ a_d,
    __half* __restrict__ Hh, float* __restrict__ asrc, float* __restrict__ adst, int n){
  constexpr int KS = K / 32;
  constexpr int NT = J / 16;
  constexpr int CPR = K / 8;
  constexpr int NTPH = NT / HEADS;
  __shared__ uint4 Alds[64 * 16];
  int t = threadIdx.x;
  int rbase = blockIdx.x * 64;

  for (int i = t; i < 64 * CPR; i += 256){
    int r = i / CPR, c = i % CPR;
    int gr = rbase + r;
    uint4 v = make_uint4(0u, 0u, 0u, 0u);
    if (gr < n){
      if (AF16){
        v = ((const uint4*)Ain)[(size_t)gr * CPR + c];
      } else {
        const float4* af = (const float4*)Ain + (size_t)gr * (K / 4) + c * 2;
        float4 lo = af[0], hi = af[1];
        __half2 p0 = __floats2half2_rn(lo.x, lo.y);
        __half2 p1 = __floats2half2_rn(lo.z, lo.w);
        __half2 p2 = __floats2half2_rn(hi.x, hi.y);
        __half2 p3 = __floats2half2_rn(hi.z, hi.w);
        v.x = *reinterpret_cast<unsigned*>(&p0);
        v.y = *reinterpret_cast<unsigned*>(&p1);
        v.z = *reinterpret_cast<unsigned*>(&p2);
        v.w = *reinterpret_cast<unsigned*>(&p3);
      }
    }
    Alds[r * 16 + (c ^ (r & 7))] = v;
  }
  __syncthreads();

  int l = t & 63;
  int wrow = (t >> 6) * 16;
  int sub = l & 15;
  int lk = l >> 4;
  f32x4 acc[NT];
  #pragma unroll
  for (int i = 0; i < NT; i++) acc[i] = (f32x4){0.f, 0.f, 0.f, 0.f};

  for (int kk = 0; kk < KS; kk++){
    int trow = wrow + sub;
    int c = kk * 4 + lk;
    f16x8 a = *reinterpret_cast<const f16x8*>(&Alds[trow * 16 + (c ^ (trow & 7))]);
    const uint4* wb = Wf + (size_t)(kk * NT) * 64 + l;
    #pragma unroll
    for (int nt = 0; nt < NT; nt++){
      uint4 wv = wb[nt * 64];
      f16x8 bfr = *reinterpret_cast<const f16x8*>(&wv);
      acc[nt] = __builtin_amdgcn_mfma_f32_16x16x32_f16(a, bfr, acc[nt], 0, 0, 0);
    }
  }

  float ps[HEADS][4], pd[HEADS][4];
  #pragma unroll
  for (int h = 0; h < HEADS; h++)
    #pragma unroll
    for (int r = 0; r < 4; r++){ ps[h][r] = 0.f; pd[h][r] = 0.f; }
  #pragma unroll
  for (int nt = 0; nt < NT; nt++){
    int h = nt / NTPH;
    float sa = a_s[nt * 16 + sub];
    float sd = a_d[nt * 16 + sub];
    #pragma unroll
    for (int r = 0; r < 4; r++){ ps[h][r] += acc[nt][r] * sa; pd[h][r] += acc[nt][r] * sd; }
  }
  #pragma unroll
  for (int h = 0; h < HEADS; h++)
    #pragma unroll
    for (int r = 0; r < 4; r++)
      #pragma unroll
      for (int d = 1; d < 16; d <<= 1){
        ps[h][r] += __shfl_xor(ps[h][r], d);
        pd[h][r] += __shfl_xor(pd[h][r], d);
      }

  #pragma unroll
  for (int r = 0; r < 4; r++){
    int gr = rbase + wrow + lk * 4 + r;
    if (gr < n){
      #pragma unroll
      for (int nt = 0; nt < NT; nt++)
        Hh[(size_t)gr * J + nt * 16 + sub] = __float2half(acc[nt][r]);
    }
  }
  #pragma unroll
  for (int h = 0; h < HEADS; h++){
    if (sub == h){
      #pragma unroll
      for (int r = 0; r < 4; r++){
        int gr = rbase + wrow + lk * 4 + r;
        if (gr < n){
          asrc[gr * HEADS + h] = ps[h][r];
          adst[gr * HEADS + h] = pd[h][r];
        }
      }
    }
  }
}

// ---------------- aggregation ----------------
template<int HEADS, int C, bool ELU, bool OUT16>
__global__ void agg_k(const __half* __restrict__ Hh,
                      const float* __restrict__ asrc, const float* __restrict__ adst,
                      const int* __restrict__ row_ptr, const int* __restrict__ esrc,
                      const float* __restrict__ bias, void* __restrict__ outv, int n){
  constexpr int J = HEADS * C;
  constexpr int NL = J / 2;
  int node = blockIdx.x * (blockDim.x >> 6) + (threadIdx.x >> 6);
  if (node >= n) return;
  int lane = threadIdx.x & 63;
  if (lane >= NL) return;
  int c0 = 2 * lane;
  int hh = c0 / C;
  const __half2* hp = (const __half2*)Hh;

  float ad = adst[node * HEADS + hh];
  float wself = __expf(lrelu(asrc[node * HEADS + hh] + ad));
  float2 hs = __half22float2(hp[(size_t)node * NL + lane]);
  float acc0 = wself * hs.x, acc1 = wself * hs.y, den = wself;

  int beg = row_ptr[node], end = row_ptr[node + 1];
  int e = beg;
  for (; e + 4 <= end; e += 4){
    int s[4]; float w[4]; float2 h[4];
    #pragma unroll
    for (int u = 0; u < 4; u++) s[u] = esrc[e + u];
    #pragma unroll
    for (int u = 0; u < 4; u++) w[u] = __expf(lrelu(asrc[s[u] * HEADS + hh] + ad));
    #pragma unroll
    for (int u = 0; u < 4; u++) h[u] = __half22float2(hp[(size_t)s[u] * NL + lane]);
    #pragma unroll
    for (int u = 0; u < 4; u++){ acc0 += w[u] * h[u].x; acc1 += w[u] * h[u].y; den += w[u]; }
  }
  for (; e < end; e++){
    int s = esrc[e];
    float w = __expf(lrelu(asrc[s * HEADS + hh] + ad));
    float2 h = __half22float2(hp[(size_t)s * NL + lane]);
    acc0 += w * h.x; acc1 += w * h.y; den += w;
  }
  float inv = 1.f / (den + EPS_);
  float r0 = acc0 * inv + bias[c0];
  float r1 = acc1 * inv + bias[c0 + 1];
  if (ELU){
    r0 = r0 > 0.f ? r0 : __expf(r0) - 1.f;
    r1 = r1 > 0.f ? r1 : __expf(r1) - 1.f;
  }
  if (OUT16){
    ((__half2*)outv)[(size_t)node * NL + lane] = __floats2half2_rn(r0, r1);
  } else {
    *reinterpret_cast<float2*>((float*)outv + (size_t)node * J + c0) = make_float2(r0, r1);
  }
}

extern "C" void kernel_launch(void* const* d_in, const int* in_sizes, int n_in,
                              void* d_out, int out_size, void* d_ws, size_t ws_size,
                              hipStream_t stream){
  const float* x   = (const float*)d_in[0];
  const int*   ei  = (const int*)  d_in[1];
  const float* W1  = (const float*)d_in[2];
  const float* as1 = (const float*)d_in[3];
  const float* ad1 = (const float*)d_in[4];
  const float* b1  = (const float*)d_in[5];
  const float* W2  = (const float*)d_in[6];
  const float* as2 = (const float*)d_in[7];
  const float* ad2 = (const float*)d_in[8];
  const float* b2  = (const float*)d_in[9];
  const float* W3  = (const float*)d_in[10];
  const float* as3 = (const float*)d_in[11];
  const float* ad3 = (const float*)d_in[12];
  const float* b3  = (const float*)d_in[13];
  float* out = (float*)d_out;

  const int N = N_NODES_C;
  const int E = in_sizes[1] / 2;
  const int* srcv = ei;
  const int* dstv = ei + E;

  char* ws = (char*)d_ws;
  auto alloc = [&](size_t bytes)->char*{ char* p = ws; ws += (bytes + 255) & ~(size_t)255; return p; };
  int*      counts  = (int*)     alloc((size_t)N * 4);
  int*      row_ptr = (int*)     alloc((size_t)(N + 1) * 4);
  int*      fill    = (int*)     alloc((size_t)N * 4);
  int*      csums   = (int*)     alloc(64 * 4);
  int*      coffs   = (int*)     alloc(64 * 4);
  int*      bcur    = (int*)     alloc(NBKT * 4);
  int*      esrc    = (int*)     alloc((size_t)E * 4);
  unsigned* ebuf    = (unsigned*)alloc((size_t)E * 4);
  __half*   Hh      = (__half*)  alloc((size_t)N * 128 * 2);
  __half*   feat_h  = (__half*)  alloc((size_t)N * 96 * 2);
  float*    a_src   = (float*)   alloc((size_t)N * 3 * 4);
  float*    a_dst   = (float*)   alloc((size_t)N * 3 * 4);
  uint4*    Wf1     = (uint4*)   alloc(128 * 96 * 2);
  uint4*    Wf2     = (uint4*)   alloc(96 * 96 * 2);
  uint4*    Wf3     = (uint4*)   alloc(96 * 128 * 2);

  // ---- CSR (by dst), bucketed build ----
  hipMemsetAsync(counts, 0, (size_t)N * 4, stream);
  hist_k<<<(E + 255) / 256, 256, 0, stream>>>(dstv, counts, E);
  int nch = (N + 1023) / 1024;
  chunksum_k<<<nch, 256, 0, stream>>>(counts, csums, N);
  chunkscan_k<<<1, 64, 0, stream>>>(csums, coffs, row_ptr, nch, N);
  scan_k<<<nch, 1024, 0, stream>>>(counts, coffs, row_ptr, fill, N);
  binit_k<<<1, 256, 0, stream>>>(row_ptr, bcur);
  bucket_k<<<(E + BATCH - 1) / BATCH, 256, 0, stream>>>(srcv, dstv, bcur, ebuf, E);
  bsort_k<<<NBKT, 256, 0, stream>>>(ebuf, row_ptr, esrc, N);

  // ---- W repacks (tiny) ----
  wpack_k<128, 96><<<6, 256, 0, stream>>>(W1, Wf1);
  wpack_k<96, 96><<<5, 256, 0, stream>>>(W2, Wf2);
  wpack_k<96, 128><<<6, 256, 0, stream>>>(W3, Wf3);

  int gnode4 = (N + 3) / 4;
  int ggemm  = (N + 63) / 64;

  // ---- layer 1: 128 -> (3,32), concat, ELU ----
  gemm_mfma_k<128, 96, 3, false><<<ggemm, 256, 0, stream>>>(x, Wf1, as1, ad1, Hh, a_src, a_dst, N);
  agg_k<3, 32, true, true><<<gnode4, 256, 0, stream>>>(Hh, a_src, a_dst, row_ptr, esrc, b1, feat_h, N);

  // ---- layer 2: 96 -> (3,32), concat, ELU ----
  gemm_mfma_k<96, 96, 3, true><<<ggemm, 256, 0, stream>>>(feat_h, Wf2, as2, ad2, Hh, a_src, a_dst, N);
  agg_k<3, 32, true, true><<<gnode4, 256, 0, stream>>>(Hh, a_src, a_dst, row_ptr, esrc, b2, feat_h, N);

  // ---- layer 3: 96 -> (1,128), mean(=identity for 1 head), no ELU ----
  gemm_mfma_k<96, 128, 1, true><<<ggemm, 256, 0, stream>>>(feat_h, Wf3, as3, ad3, Hh, a_src, a_dst, N);
  agg_k<1, 128, false, false><<<gnode4, 256, 0, stream>>>(Hh, a_src, a_dst, row_ptr, esrc, b3, out, N);
}

// Round 10
// 326.810 us; speedup vs baseline: 2.5882x; 1.0258x over previous
//
#include <hip/hip_runtime.h>
#include <hip/hip_bf16.h>
#include <hip/hip_fp16.h>
#include <math.h>

#define N_NODES_C 50000
#define NBKT ((N_NODES_C + 255) / 256)   // 196 buckets of 256 nodes
#define NEG_SLOPE 0.2f
#define EPS_ 1e-16f

typedef _Float16 f16x8 __attribute__((ext_vector_type(8)));
typedef float    f32x4 __attribute__((ext_vector_type(4)));

__device__ __forceinline__ float lrelu(float x){ return x > 0.f ? x : NEG_SLOPE * x; }

// ---------------- CSR build ----------------
__global__ void hist_k(const int* __restrict__ dstv, int* __restrict__ counts, int E){
  int t = blockIdx.x * blockDim.x + threadIdx.x;
  if (t < E) atomicAdd(&counts[dstv[t]], 1);
}

__global__ void chunksum_k(const int* __restrict__ counts, int* __restrict__ sums, int n){
  __shared__ int lds[4];
  int base = blockIdx.x * 1024;
  int t = threadIdx.x; // 256
  int s = 0;
  for (int i = t; i < 1024; i += 256){ int idx = base + i; s += (idx < n) ? counts[idx] : 0; }
  for (int d = 32; d >= 1; d >>= 1) s += __shfl_xor(s, d);
  if ((t & 63) == 0) lds[t >> 6] = s;
  __syncthreads();
  if (t == 0) sums[blockIdx.x] = lds[0] + lds[1] + lds[2] + lds[3];
}

// scan with fused chunk-offset (csums sum) and bcur init. nch <= 64.
__global__ void scan_k(const int* __restrict__ counts, const int* __restrict__ csums,
                       int* __restrict__ row_ptr, int* __restrict__ bcur, int nch, int n){
  __shared__ int ws[16];
  __shared__ int boff;
  int base = blockIdx.x * 1024; int t = threadIdx.x; int idx = base + t;
  int v = (idx < n) ? counts[idx] : 0;
  int lane = t & 63, wid = t >> 6;
  int x = v;
  for (int d = 1; d < 64; d <<= 1){ int y = __shfl_up(x, d); if (lane >= d) x += y; }
  if (lane == 63) ws[wid] = x;
  if (t < 64){
    int c = (t < blockIdx.x) ? csums[t] : 0;
    for (int d = 32; d >= 1; d >>= 1) c += __shfl_xor(c, d);
    if (t == 0) boff = c;
  }
  __syncthreads();
  if (t < 16){ int y = ws[t]; for (int d = 1; d < 16; d <<= 1){ int z = __shfl_up(y, d); if (t >= d) y += z; } ws[t] = y; }
  __syncthreads();
  int excl = x - v + (wid ? ws[wid - 1] : 0) + boff;
  if (idx < n){
    row_ptr[idx] = excl;
    if ((idx & 255) == 0) bcur[idx >> 8] = excl;
  }
  if (blockIdx.x == nch - 1 && t == 0) row_ptr[n] = boff + ws[15];
}

// phase 1: classify edges into 196 dst-buckets with LDS staging, contiguous flushes.
#define BATCH 2048
#define BCAP 32
__global__ __launch_bounds__(256) void bucket_k(const int* __restrict__ srcv, const int* __restrict__ dstv,
                                                int* __restrict__ bcur, unsigned* __restrict__ ebuf, int E){
  __shared__ unsigned stage[NBKT * BCAP];   // 25 KB
  __shared__ int cnt[NBKT];
  int t = threadIdx.x;
  int start = blockIdx.x * BATCH;
  int end = start + BATCH; if (end > E) end = E;
  for (int i = t; i < NBKT; i += 256) cnt[i] = 0;
  __syncthreads();
  for (int e = start + t; e < end; e += 256){
    int s = srcv[e], d = dstv[e];
    int b = d >> 8;
    unsigned entry = (unsigned)s | ((unsigned)(d & 255) << 16);
    int pos = atomicAdd(&cnt[b], 1);
    if (pos < BCAP) stage[b * BCAP + pos] = entry;
    else { int p = atomicAdd(&bcur[b], 1); ebuf[p] = entry; }   // rare overflow
  }
  __syncthreads();
  if (t < NBKT){
    int c = cnt[t]; if (c > BCAP) c = BCAP;
    if (c > 0){
      int p = atomicAdd(&bcur[t], c);
      for (int i = 0; i < c; i++) ebuf[p + i] = stage[t * BCAP + i];
    }
  }
}

// phase 2: one block owns one bucket; rank edges per node via LDS counters.
__global__ __launch_bounds__(256) void bsort_k(const unsigned* __restrict__ ebuf,
                                               const int* __restrict__ row_ptr,
                                               int* __restrict__ esrc, int n){
  __shared__ int cnt[256];
  int b = blockIdx.x;
  int nb = b * 256;
  int t = threadIdx.x;
  cnt[t] = 0;
  __syncthreads();
  int hi_node = nb + 256; if (hi_node > n) hi_node = n;
  int beg = row_ptr[nb], end = row_ptr[hi_node];
  for (int i = beg + t; i < end; i += 256){
    unsigned e = ebuf[i];
    int dl = e >> 16;
    int src = (int)(e & 0xFFFFu);
    int rank = atomicAdd(&cnt[dl], 1);
    esrc[row_ptr[nb + dl] + rank] = src;
  }
}

// ---------------- W repack to MFMA B-fragment order (fp16), all 3 in one launch ----------------
template<int K, int J>
__device__ void wpack_dev(const float* __restrict__ W, uint4* __restrict__ Wf, int blk, int nblk){
  constexpr int KS = K / 32, NT = J / 16;
  int tot = KS * NT * 64;
  for (int t = blk * 256 + threadIdx.x; t < tot; t += nblk * 256){
    int l = t & 63;
    int nt = (t >> 6) % NT;
    int kk = t / (64 * NT);
    int col = nt * 16 + (l & 15);
    int k0 = kk * 32 + (l >> 4) * 8;
    unsigned u[4];
    #pragma unroll
    for (int p = 0; p < 4; p++){
      __half2 h = __floats2half2_rn(W[(k0 + 2 * p) * J + col], W[(k0 + 2 * p + 1) * J + col]);
      u[p] = *reinterpret_cast<unsigned*>(&h);
    }
    uint4 v; v.x = u[0]; v.y = u[1]; v.z = u[2]; v.w = u[3];
    Wf[t] = v;
  }
}

__global__ void wpack_all_k(const float* W1, const float* W2, const float* W3,
                            uint4* Wf1, uint4* Wf2, uint4* Wf3){
  int b = blockIdx.x;
  if (b < 6) wpack_dev<128, 96>(W1, Wf1, b, 6);
  else if (b < 11) wpack_dev<96, 96>(W2, Wf2, b - 6, 5);
  else wpack_dev<96, 128>(W3, Wf3, b - 11, 6);
}

// ---------------- MFMA GEMM + alpha ----------------
template<int K, int J, int HEADS, bool AF16>
__global__ __launch_bounds__(256) void gemm_mfma_k(
    const void* __restrict__ Ain, const uint4* __restrict__ Wf,
    const float* __restrict__ a_s, const float* __restrict__ a_d,
    __half* __restrict__ Hh, float* __restrict__ asrc, float* __restrict__ adst, int n){
  constexpr int KS = K / 32;
  constexpr int NT = J / 16;
  constexpr int CPR = K / 8;
  constexpr int NTPH = NT / HEADS;
  __shared__ uint4 Alds[64 * 16];
  int t = threadIdx.x;
  int rbase = blockIdx.x * 64;

  for (int i = t; i < 64 * CPR; i += 256){
    int r = i / CPR, c = i % CPR;
    int gr = rbase + r;
    uint4 v = make_uint4(0u, 0u, 0u, 0u);
    if (gr < n){
      if (AF16){
        v = ((const uint4*)Ain)[(size_t)gr * CPR + c];
      } else {
        const float4* af = (const float4*)Ain + (size_t)gr * (K / 4) + c * 2;
        float4 lo = af[0], hi = af[1];
        __half2 p0 = __floats2half2_rn(lo.x, lo.y);
        __half2 p1 = __floats2half2_rn(lo.z, lo.w);
        __half2 p2 = __floats2half2_rn(hi.x, hi.y);
        __half2 p3 = __floats2half2_rn(hi.z, hi.w);
        v.x = *reinterpret_cast<unsigned*>(&p0);
        v.y = *reinterpret_cast<unsigned*>(&p1);
        v.z = *reinterpret_cast<unsigned*>(&p2);
        v.w = *reinterpret_cast<unsigned*>(&p3);
      }
    }
    Alds[r * 16 + (c ^ (r & 7))] = v;
  }
  __syncthreads();

  int l = t & 63;
  int wrow = (t >> 6) * 16;
  int sub = l & 15;
  int lk = l >> 4;
  f32x4 acc[NT];
  #pragma unroll
  for (int i = 0; i < NT; i++) acc[i] = (f32x4){0.f, 0.f, 0.f, 0.f};

  for (int kk = 0; kk < KS; kk++){
    int trow = wrow + sub;
    int c = kk * 4 + lk;
    f16x8 a = *reinterpret_cast<const f16x8*>(&Alds[trow * 16 + (c ^ (trow & 7))]);
    const uint4* wb = Wf + (size_t)(kk * NT) * 64 + l;
    #pragma unroll
    for (int nt = 0; nt < NT; nt++){
      uint4 wv = wb[nt * 64];
      f16x8 bfr = *reinterpret_cast<const f16x8*>(&wv);
      acc[nt] = __builtin_amdgcn_mfma_f32_16x16x32_f16(a, bfr, acc[nt], 0, 0, 0);
    }
  }

  float ps[HEADS][4], pd[HEADS][4];
  #pragma unroll
  for (int h = 0; h < HEADS; h++)
    #pragma unroll
    for (int r = 0; r < 4; r++){ ps[h][r] = 0.f; pd[h][r] = 0.f; }
  #pragma unroll
  for (int nt = 0; nt < NT; nt++){
    int h = nt / NTPH;
    float sa = a_s[nt * 16 + sub];
    float sd = a_d[nt * 16 + sub];
    #pragma unroll
    for (int r = 0; r < 4; r++){ ps[h][r] += acc[nt][r] * sa; pd[h][r] += acc[nt][r] * sd; }
  }
  #pragma unroll
  for (int h = 0; h < HEADS; h++)
    #pragma unroll
    for (int r = 0; r < 4; r++)
      #pragma unroll
      for (int d = 1; d < 16; d <<= 1){
        ps[h][r] += __shfl_xor(ps[h][r], d);
        pd[h][r] += __shfl_xor(pd[h][r], d);
      }

  #pragma unroll
  for (int r = 0; r < 4; r++){
    int gr = rbase + wrow + lk * 4 + r;
    if (gr < n){
      #pragma unroll
      for (int nt = 0; nt < NT; nt++)
        Hh[(size_t)gr * J + nt * 16 + sub] = __float2half(acc[nt][r]);
    }
  }
  #pragma unroll
  for (int h = 0; h < HEADS; h++){
    if (sub == h){
      #pragma unroll
      for (int r = 0; r < 4; r++){
        int gr = rbase + wrow + lk * 4 + r;
        if (gr < n){
          asrc[gr * HEADS + h] = ps[h][r];
          adst[gr * HEADS + h] = pd[h][r];
        }
      }
    }
  }
}

// ---------------- aggregation: wave per dst node; shared weight lanes + 8-deep gather pipeline ----------------
template<int HEADS, int C, bool ELU, bool OUT16>
__global__ void agg_k(const __half* __restrict__ Hh,
                      const float* __restrict__ asrc, const float* __restrict__ adst,
                      const int* __restrict__ row_ptr, const int* __restrict__ esrc,
                      const float* __restrict__ bias, void* __restrict__ outv, int n){
  constexpr int J = HEADS * C;
  constexpr int NL = J / 2;              // active column lanes
  constexpr int WL0 = 64 - 8 * HEADS;    // weight lanes: WL0..63 handle 8 edges x HEADS
  int node = blockIdx.x * (blockDim.x >> 6) + (threadIdx.x >> 6);
  if (node >= n) return;
  int lane = threadIdx.x & 63;
  bool colact = (NL == 64) || (lane < NL);
  int cl = colact ? lane : 0;            // clamped column lane
  int c0 = 2 * cl;
  int hh = c0 / C;
  const __half2* hp = (const __half2*)Hh;

  // weight-lane role
  int wl = lane - WL0; if (wl < 0) wl = 0;
  int wu, wh;
  if (HEADS == 3){ wu = wl / 3; wh = wl - wu * 3; } else { wu = wl; wh = 0; }

  float ad_own = adst[node * HEADS + hh];
  float ad_w = (HEADS == 3) ? __shfl(ad_own, wh * 16) : ad_own;

  float wself = __expf(lrelu(asrc[node * HEADS + hh] + ad_own));
  float2 hs = __half22float2(hp[(size_t)node * NL + cl]);
  float acc0 = wself * hs.x, acc1 = wself * hs.y, den = wself;

  int beg = row_ptr[node], end = row_ptr[node + 1];
  int e = beg;
  for (; e + 8 <= end; e += 8){
    int s0 = esrc[e],     s1 = esrc[e + 1], s2 = esrc[e + 2], s3 = esrc[e + 3];
    int s4 = esrc[e + 4], s5 = esrc[e + 5], s6 = esrc[e + 6], s7 = esrc[e + 7];
    // weight lanes: one gather + lrelu + exp for their (edge,head)
    int ssel = wu < 4 ? (wu < 2 ? (wu == 0 ? s0 : s1) : (wu == 2 ? s2 : s3))
                      : (wu < 6 ? (wu == 4 ? s4 : s5) : (wu == 6 ? s6 : s7));
    float wv = __expf(lrelu(asrc[ssel * HEADS + wh] + ad_w));
    // broadcast weights
    float w0 = __shfl(wv, WL0 + 0 * HEADS + hh);
    float w1 = __shfl(wv, WL0 + 1 * HEADS + hh);
    float w2 = __shfl(wv, WL0 + 2 * HEADS + hh);
    float w3 = __shfl(wv, WL0 + 3 * HEADS + hh);
    float w4 = __shfl(wv, WL0 + 4 * HEADS + hh);
    float w5 = __shfl(wv, WL0 + 5 * HEADS + hh);
    float w6 = __shfl(wv, WL0 + 6 * HEADS + hh);
    float w7 = __shfl(wv, WL0 + 7 * HEADS + hh);
    // 8 feature gathers in flight
    __half2 u0 = hp[(size_t)s0 * NL + cl];
    __half2 u1 = hp[(size_t)s1 * NL + cl];
    __half2 u2 = hp[(size_t)s2 * NL + cl];
    __half2 u3 = hp[(size_t)s3 * NL + cl];
    __half2 u4 = hp[(size_t)s4 * NL + cl];
    __half2 u5 = hp[(size_t)s5 * NL + cl];
    __half2 u6 = hp[(size_t)s6 * NL + cl];
    __half2 u7 = hp[(size_t)s7 * NL + cl];
    float2 f0 = __half22float2(u0), f1 = __half22float2(u1);
    float2 f2 = __half22float2(u2), f3 = __half22float2(u3);
    float2 f4 = __half22float2(u4), f5 = __half22float2(u5);
    float2 f6 = __half22float2(u6), f7 = __half22float2(u7);
    acc0 += w0 * f0.x; acc1 += w0 * f0.y; den += w0;
    acc0 += w1 * f1.x; acc1 += w1 * f1.y; den += w1;
    acc0 += w2 * f2.x; acc1 += w2 * f2.y; den += w2;
    acc0 += w3 * f3.x; acc1 += w3 * f3.y; den += w3;
    acc0 += w4 * f4.x; acc1 += w4 * f4.y; den += w4;
    acc0 += w5 * f5.x; acc1 += w5 * f5.y; den += w5;
    acc0 += w6 * f6.x; acc1 += w6 * f6.y; den += w6;
    acc0 += w7 * f7.x; acc1 += w7 * f7.y; den += w7;
  }
  for (; e < end; e++){
    int s = esrc[e];
    float w = __expf(lrelu(asrc[s * HEADS + hh] + ad_own));
    float2 h = __half22float2(hp[(size_t)s * NL + cl]);
    acc0 += w * h.x; acc1 += w * h.y; den += w;
  }
  if (colact){
    float inv = 1.f / (den + EPS_);
    float r0 = acc0 * inv + bias[c0];
    float r1 = acc1 * inv + bias[c0 + 1];
    if (ELU){
      r0 = r0 > 0.f ? r0 : __expf(r0) - 1.f;
      r1 = r1 > 0.f ? r1 : __expf(r1) - 1.f;
    }
    if (OUT16){
      ((__half2*)outv)[(size_t)node * NL + cl] = __floats2half2_rn(r0, r1);
    } else {
      *reinterpret_cast<float2*>((float*)outv + (size_t)node * J + c0) = make_float2(r0, r1);
    }
  }
}

extern "C" void kernel_launch(void* const* d_in, const int* in_sizes, int n_in,
                              void* d_out, int out_size, void* d_ws, size_t ws_size,
                              hipStream_t stream){
  const float* x   = (const float*)d_in[0];
  const int*   ei  = (const int*)  d_in[1];
  const float* W1  = (const float*)d_in[2];
  const float* as1 = (const float*)d_in[3];
  const float* ad1 = (const float*)d_in[4];
  const float* b1  = (const float*)d_in[5];
  const float* W2  = (const float*)d_in[6];
  const float* as2 = (const float*)d_in[7];
  const float* ad2 = (const float*)d_in[8];
  const float* b2  = (const float*)d_in[9];
  const float* W3  = (const float*)d_in[10];
  const float* as3 = (const float*)d_in[11];
  const float* ad3 = (const float*)d_in[12];
  const float* b3  = (const float*)d_in[13];
  float* out = (float*)d_out;

  const int N = N_NODES_C;
  const int E = in_sizes[1] / 2;
  const int* srcv = ei;
  const int* dstv = ei + E;

  char* ws = (char*)d_ws;
  auto alloc = [&](size_t bytes)->char*{ char* p = ws; ws += (bytes + 255) & ~(size_t)255; return p; };
  int*      counts  = (int*)     alloc((size_t)N * 4);
  int*      row_ptr = (int*)     alloc((size_t)(N + 1) * 4);
  int*      csums   = (int*)     alloc(64 * 4);
  int*      bcur    = (int*)     alloc(NBKT * 4);
  int*      esrc    = (int*)     alloc((size_t)E * 4);
  unsigned* ebuf    = (unsigned*)alloc((size_t)E * 4);
  __half*   Hh      = (__half*)  alloc((size_t)N * 128 * 2);
  __half*   feat_h  = (__half*)  alloc((size_t)N * 96 * 2);
  float*    a_src   = (float*)   alloc((size_t)N * 3 * 4);
  float*    a_dst   = (float*)   alloc((size_t)N * 3 * 4);
  uint4*    Wf1     = (uint4*)   alloc(128 * 96 * 2);
  uint4*    Wf2     = (uint4*)   alloc(96 * 96 * 2);
  uint4*    Wf3     = (uint4*)   alloc(96 * 128 * 2);

  // ---- CSR (by dst), bucketed build ----
  hipMemsetAsync(counts, 0, (size_t)N * 4, stream);
  hist_k<<<(E + 255) / 256, 256, 0, stream>>>(dstv, counts, E);
  int nch = (N + 1023) / 1024;
  chunksum_k<<<nch, 256, 0, stream>>>(counts, csums, N);
  scan_k<<<nch, 1024, 0, stream>>>(counts, csums, row_ptr, bcur, nch, N);
  bucket_k<<<(E + BATCH - 1) / BATCH, 256, 0, stream>>>(srcv, dstv, bcur, ebuf, E);
  bsort_k<<<NBKT, 256, 0, stream>>>(ebuf, row_ptr, esrc, N);

  // ---- W repacks (one launch) ----
  wpack_all_k<<<17, 256, 0, stream>>>(W1, W2, W3, Wf1, Wf2, Wf3);

  int gnode4 = (N + 3) / 4;
  int ggemm  = (N + 63) / 64;

  // ---- layer 1: 128 -> (3,32), concat, ELU ----
  gemm_mfma_k<128, 96, 3, false><<<ggemm, 256, 0, stream>>>(x, Wf1, as1, ad1, Hh, a_src, a_dst, N);
  agg_k<3, 32, true, true><<<gnode4, 256, 0, stream>>>(Hh, a_src, a_dst, row_ptr, esrc, b1, feat_h, N);

  // ---- layer 2: 96 -> (3,32), concat, ELU ----
  gemm_mfma_k<96, 96, 3, true><<<ggemm, 256, 0, stream>>>(feat_h, Wf2, as2, ad2, Hh, a_src, a_dst, N);
  agg_k<3, 32, true, true><<<gnode4, 256, 0, stream>>>(Hh, a_src, a_dst, row_ptr, esrc, b2, feat_h, N);

  // ---- layer 3: 96 -> (1,128), mean(=identity for 1 head), no ELU ----
  gemm_mfma_k<96, 128, 1, true><<<ggemm, 256, 0, stream>>>(feat_h, Wf3, as3, ad3, Hh, a_src, a_dst, N);
  agg_k<1, 128, false, false><<<gnode4, 256, 0, stream>>>(Hh, a_src, a_dst, row_ptr, esrc, b3, out, N);
}